// Round 12
// baseline (580.666 us; speedup 1.0000x reference)
//
#include <hip/hip_runtime.h>
#include <math.h>

#define CNW 9216000      // C*N*W = 96*1000*96
#define TOT 18432000     // B*C*N*W
#define EPSV 1e-5f
#define ITEMP 0.10206207261596575f   // 1/sqrt(96)
#define NREP 16          // stats replicas (breaks same-address atomic chains)

typedef __attribute__((ext_vector_type(8))) short bf16x8;   // 8 bf16 = 4 VGPR
typedef __attribute__((ext_vector_type(4))) float f32x4;

union FragU { unsigned u[4]; bf16x8 v; };

// round-to-nearest-even fp32 -> bf16 (upper 16 bits)
__device__ __forceinline__ unsigned bfr(float x) {
  union { float f; unsigned u; } v; v.f = x;
  return (v.u + 0x7fffu + ((v.u >> 16) & 1u)) >> 16;
}
__device__ __forceinline__ float eluf(float x) {
  return fmaxf(x, 0.f) + __expf(fminf(x, 0.f)) - 1.f;
}
// unpack bf16 pair (u32) -> fp32 (exact: bf16 is fp32's upper 16 bits)
__device__ __forceinline__ float blo(unsigned u) {
  union { unsigned x; float f; } v; v.x = u << 16; return v.f;
}
__device__ __forceinline__ float bhi(unsigned u) {
  union { unsigned x; float f; } v; v.x = u & 0xffff0000u; return v.f;
}

// =============== prep: pack weights into bf16 k-pair layout =================
__global__ __launch_bounds__(256) void prep0_k(const float* __restrict__ w,
                                               unsigned* __restrict__ w2g) {
  int t = threadIdx.x;
  for (int i = t; i < 4704; i += 256) {
    int o = i / 49, c2 = i % 49;
    unsigned p = 0;
    if (c2 < 48) p = bfr(w[o * 96 + 2 * c2]) | (bfr(w[o * 96 + 2 * c2 + 1]) << 16);
    w2g[i] = p;
  }
}

// collapse GN replicas, fold GN scale into w_right/w_l1 (per b), exact bias2
__global__ __launch_bounds__(256) void prep_rl_k(const float* __restrict__ rawGN,
    const float* __restrict__ wR, const float* __restrict__ bR,
    const float* __restrict__ wL, const float* __restrict__ bL,
    const float* __restrict__ gnw, const float* __restrict__ gnb,
    unsigned* __restrict__ w2R, float* __restrict__ b2R,
    unsigned* __restrict__ w2L, float* __restrict__ b2L) {
  __shared__ float stGN[24];
  __shared__ float scl[2][96], sh[2][96];
  int t = threadIdx.x;
  if (t < 24) {
    float s = 0.f;
    for (int r = 0; r < NREP; ++r) s += rawGN[r * 24 + t];
    stGN[t] = s;
  }
  __syncthreads();
  if (t < 192) {
    int b = t / 96, c = t % 96, g = c >> 4;
    float m = stGN[b * 12 + g * 2] * (1.f / 1536000.f);
    float v = stGN[b * 12 + g * 2 + 1] * (1.f / 1536000.f) - m * m;
    float sc = rsqrtf(v + EPSV) * gnw[c];
    scl[b][c] = sc;
    sh[b][c] = gnb[c] - m * sc;
  }
  __syncthreads();
  for (int i = t; i < 2 * 2 * 4704; i += 256) {
    int wsel = i / 9408, rem = i % 9408, b = rem / 4704, j = rem % 4704;
    int o = j / 49, c2 = j % 49;
    const float* W = wsel ? wL : wR;
    unsigned p = 0;
    if (c2 < 48) {
      float w0 = W[o * 96 + 2 * c2] * scl[b][2 * c2];
      float w1 = W[o * 96 + 2 * c2 + 1] * scl[b][2 * c2 + 1];
      p = bfr(w0) | (bfr(w1) << 16);
    }
    (wsel ? w2L : w2R)[b * 4704 + j] = p;
  }
  for (int i = t; i < 2 * 2 * 96; i += 256) {
    int wsel = i / 192, rem = i % 192, b = rem / 96, o = rem % 96;
    const float* W = wsel ? wL : wR;
    float acc = (wsel ? bL : bR)[o];
    for (int c = 0; c < 96; ++c) acc += W[o * 96 + c] * sh[b][c];
    (wsel ? b2L : b2R)[b * 96 + o] = acc;
  }
}

// collapse IN1 replicas, compute BN1(IN) affine, pack w_l2 (unscaled)
__global__ __launch_bounds__(256) void prep_l2_k(const float* __restrict__ rawIN1,
    const float* __restrict__ w, const float* __restrict__ bi,
    const float* __restrict__ bn1w, const float* __restrict__ bn1b,
    unsigned* __restrict__ w2g, float* __restrict__ b2g,
    float* __restrict__ sclg, float* __restrict__ shfg) {
  __shared__ float st[384];
  int t = threadIdx.x;
  for (int i = t; i < 384; i += 256) {
    float s = 0.f;
    for (int r = 0; r < NREP; ++r) s += rawIN1[r * 384 + i];
    st[i] = s;
  }
  __syncthreads();
  if (t < 192) {
    int b = t / 96, c = t % 96;
    const float inv = 1.f / 96000.f;
    float m0 = st[c * 2] * inv, v0 = st[c * 2 + 1] * inv - m0 * m0;
    float m1 = st[192 + c * 2] * inv, v1 = st[192 + c * 2 + 1] * inv - m1 * m1;
    float bv = 0.5f * (v0 / (v0 + EPSV) + v1 / (v1 + EPSV));
    float bscale = rsqrtf(bv + EPSV) * bn1w[c];
    float mi = b ? m1 : m0, vi = b ? v1 : v0;
    float sc = rsqrtf(vi + EPSV) * bscale;
    sclg[t] = sc;
    shfg[t] = bn1b[c] - mi * sc;
    b2g[t] = bi[c];
  }
  for (int i = t; i < 4704; i += 256) {
    int o = i / 49, c2 = i % 49;
    unsigned p = 0;
    if (c2 < 48) p = bfr(w[o * 96 + 2 * c2]) | (bfr(w[o * 96 + 2 * c2 + 1]) << 16);
    w2g[i] = p;
  }
}

// =============== conv0 via MFMA: feat & elu(feat), both bf16 ================
// x fp32 in, featb/felub bf16 out (write bytes = old fp32 single output).
// Safe for the cut: top-3 selection now runs off the exact fp32 xmean path.
__global__ __launch_bounds__(256) void convb0_k(const float* __restrict__ xin,
    const unsigned* __restrict__ w2g,
    unsigned short* __restrict__ fb, unsigned short* __restrict__ fe) {
  __shared__ __align__(16) unsigned ldsW[96 * 49];
  __shared__ __align__(16) unsigned xt2[64 * 49];
  int tile = blockIdx.x % 1500, b = blockIdx.x / 1500;
  int nw0 = tile * 64;
  int t = threadIdx.x;
  for (int i = t; i < 1176; i += 256)
    ((float4*)ldsW)[i] = ((const float4*)w2g)[i];
  const float* xb = xin + b * CNW + nw0;
  for (int i = t; i < 768; i += 256) {
    int c2 = i >> 4, j4 = i & 15;
    const float* r0 = xb + (2 * c2) * 96000 + j4 * 4;
    float4 x0 = *(const float4*)r0;
    float4 x1 = *(const float4*)(r0 + 96000);
    int base = j4 * 4;
    xt2[(base + 0) * 49 + c2] = bfr(x0.x) | (bfr(x1.x) << 16);
    xt2[(base + 1) * 49 + c2] = bfr(x0.y) | (bfr(x1.y) << 16);
    xt2[(base + 2) * 49 + c2] = bfr(x0.z) | (bfr(x1.z) << 16);
    xt2[(base + 3) * 49 + c2] = bfr(x0.w) | (bfr(x1.w) << 16);
  }
  __syncthreads();
  int lane = t & 63, nt = t >> 6;
  int l15 = lane & 15, kg = lane >> 4;
  f32x4 acc[6];
#pragma unroll
  for (int mt = 0; mt < 6; ++mt) acc[mt] = (f32x4){0.f, 0.f, 0.f, 0.f};
#pragma unroll
  for (int ks = 0; ks < 3; ++ks) {
    int cb = ks * 16 + kg * 4;
    FragU bf;
    int brow = (nt * 16 + l15) * 49 + cb;
    bf.u[0] = xt2[brow + 0]; bf.u[1] = xt2[brow + 1];
    bf.u[2] = xt2[brow + 2]; bf.u[3] = xt2[brow + 3];
#pragma unroll
    for (int mt = 0; mt < 6; ++mt) {
      FragU af;
      int arow = (mt * 16 + l15) * 49 + cb;
      af.u[0] = ldsW[arow + 0]; af.u[1] = ldsW[arow + 1];
      af.u[2] = ldsW[arow + 2]; af.u[3] = ldsW[arow + 3];
      acc[mt] = __builtin_amdgcn_mfma_f32_16x16x32_bf16(af.v, bf.v, acc[mt], 0, 0, 0);
    }
  }
  unsigned short* f1 = fb + (size_t)b * CNW + nw0 + nt * 16 + l15;
  unsigned short* f2 = fe + (size_t)b * CNW + nw0 + nt * 16 + l15;
#pragma unroll
  for (int mt = 0; mt < 6; ++mt)
#pragma unroll
    for (int r = 0; r < 4; ++r) {
      int o = mt * 16 + kg * 4 + r;
      float val = acc[mt][r];
      f1[o * 96000] = (unsigned short)bfr(val);
      f2[o * 96000] = (unsigned short)bfr(eluf(val));
    }
}

// =============== xmean: xm[b][m][cin][w] = mean_s x[b][cin][m*100+s][w] =====
// exact fp32 path feeding the discrete sinkhorn cut (qm is linear in x).
__global__ __launch_bounds__(128) void xmean_k(const float* __restrict__ x,
                                               float* __restrict__ xm) {
  int cin = blockIdx.x % 96, bm = blockIdx.x / 96;   // bm = b*10+m
  int b = bm / 10, m = bm % 10;
  int t = threadIdx.x;
  if (t < 96) {
    const float* xp = x + (size_t)(b * 96 + cin) * 96000 + m * 100 * 96 + t;
    float s = 0.f;
    for (int r = 0; r < 100; ++r) s += xp[r * 96];
    xm[(bm * 96 + cin) * 96 + t] = s * 0.01f;
  }
}

// =============== qm: per (b,m) tiny GEMM W @ xm -> qmg[head][m][j] ==========
__global__ __launch_bounds__(256) void qm_k(const float* __restrict__ xm,
    const float* __restrict__ w, float* __restrict__ qmg) {
  __shared__ float Wl[96 * 97], Xl[96 * 97];
  int b = blockIdx.x / 10, m = blockIdx.x % 10;
  int t = threadIdx.x;
  for (int i = t; i < 9216; i += 256) {
    int r = i / 96, cc = i % 96;
    Wl[r * 97 + cc] = w[i];
    Xl[r * 97 + cc] = xm[((b * 10 + m) * 96 + r) * 96 + cc];
  }
  __syncthreads();
  for (int i = t; i < 9216; i += 256) {
    int c = i / 96, ww = i % 96;
    float acc = 0.f;
    for (int k = 0; k < 96; ++k) acc += Wl[c * 97 + k] * Xl[k * 97 + ww];
    int g = ww >> 4, j = ww & 15;
    qmg[(b * 576 + c * 6 + g) * 160 + m * 16 + j] = acc;
  }
}

// ---------------- collapse NREP replicas -> canonical [384] -----------------
__global__ __launch_bounds__(256) void collapse_k(const float* __restrict__ r0,
    float* __restrict__ o0, const float* __restrict__ r1, float* __restrict__ o1) {
  int t = blockIdx.x * 256 + threadIdx.x;
  const float* r = (t < 384) ? r0 : r1;
  float* o = (t < 384) ? o0 : o1;
  int i = (t < 384) ? t : t - 384;
  if (t < 768 && r) {
    float s = 0.f;
#pragma unroll
    for (int k = 0; k < NREP; ++k) s += r[k * 384 + i];
    o[i] = s;
  }
}

// =============== MFMA conv: D[o,nw] = W[96x96] @ X[96x96000] per batch ======
template <int MODE, int STATS>
__global__ __launch_bounds__(256) void convm_k(const float* __restrict__ xin,
    const unsigned* __restrict__ w2g, const float* __restrict__ b2g,
    const float* __restrict__ sclg, const float* __restrict__ shfg,
    float* __restrict__ outp, float* __restrict__ st_out) {
  __shared__ __align__(16) unsigned ldsW[96 * 49];
  __shared__ __align__(16) unsigned xt2[64 * 49];
  __shared__ float ldsB[96], lS[96], lH[96];
  __shared__ float ssum[4 * 96], sqsum[4 * 96];
  int tile = blockIdx.x % 1500, b = blockIdx.x / 1500;
  int nw0 = tile * 64;
  int t = threadIdx.x;
  const unsigned* wsrc = w2g + (MODE == 1 ? b * 4704 : 0);
  for (int i = t; i < 1176; i += 256)
    ((float4*)ldsW)[i] = ((const float4*)wsrc)[i];
  if (t < 96) {
    ldsB[t] = (MODE == 0) ? 0.f : b2g[b * 96 + t];
    if (MODE == 2) { lS[t] = sclg[b * 96 + t]; lH[t] = shfg[b * 96 + t]; }
  }
  __syncthreads();
  const float* xb = xin + b * CNW + nw0;
  for (int i = t; i < 768; i += 256) {
    int c2 = i >> 4, j4 = i & 15;
    const float* r0 = xb + (2 * c2) * 96000 + j4 * 4;
    float4 x0 = *(const float4*)r0;
    float4 x1 = *(const float4*)(r0 + 96000);
    if (MODE == 2) {
      float s0 = lS[2 * c2], h0 = lH[2 * c2];
      float s1 = lS[2 * c2 + 1], h1 = lH[2 * c2 + 1];
      x0.x = fmaxf(x0.x * s0 + h0, 0.f); x0.y = fmaxf(x0.y * s0 + h0, 0.f);
      x0.z = fmaxf(x0.z * s0 + h0, 0.f); x0.w = fmaxf(x0.w * s0 + h0, 0.f);
      x1.x = fmaxf(x1.x * s1 + h1, 0.f); x1.y = fmaxf(x1.y * s1 + h1, 0.f);
      x1.z = fmaxf(x1.z * s1 + h1, 0.f); x1.w = fmaxf(x1.w * s1 + h1, 0.f);
    }
    int base = j4 * 4;
    xt2[(base + 0) * 49 + c2] = bfr(x0.x) | (bfr(x1.x) << 16);
    xt2[(base + 1) * 49 + c2] = bfr(x0.y) | (bfr(x1.y) << 16);
    xt2[(base + 2) * 49 + c2] = bfr(x0.z) | (bfr(x1.z) << 16);
    xt2[(base + 3) * 49 + c2] = bfr(x0.w) | (bfr(x1.w) << 16);
  }
  __syncthreads();
  int lane = t & 63, nt = t >> 6;
  int l15 = lane & 15, kg = lane >> 4;
  f32x4 acc[6];
#pragma unroll
  for (int mt = 0; mt < 6; ++mt) acc[mt] = (f32x4){0.f, 0.f, 0.f, 0.f};
#pragma unroll
  for (int ks = 0; ks < 3; ++ks) {
    int cb = ks * 16 + kg * 4;
    FragU bf;
    int brow = (nt * 16 + l15) * 49 + cb;
    bf.u[0] = xt2[brow + 0]; bf.u[1] = xt2[brow + 1];
    bf.u[2] = xt2[brow + 2]; bf.u[3] = xt2[brow + 3];
#pragma unroll
    for (int mt = 0; mt < 6; ++mt) {
      FragU af;
      int arow = (mt * 16 + l15) * 49 + cb;
      af.u[0] = ldsW[arow + 0]; af.u[1] = ldsW[arow + 1];
      af.u[2] = ldsW[arow + 2]; af.u[3] = ldsW[arow + 3];
      acc[mt] = __builtin_amdgcn_mfma_f32_16x16x32_bf16(af.v, bf.v, acc[mt], 0, 0, 0);
    }
  }
  float* ob = outp + b * CNW + nw0 + nt * 16 + l15;
  float sv[6][4], qv[6][4];
#pragma unroll
  for (int mt = 0; mt < 6; ++mt)
#pragma unroll
    for (int r = 0; r < 4; ++r) {
      int o = mt * 16 + kg * 4 + r;
      float val = acc[mt][r] + ldsB[o];
      ob[o * 96000] = val;
      if (STATS) { sv[mt][r] = val; qv[mt][r] = val * val; }
    }
  if (STATS) {
#pragma unroll
    for (int msk = 1; msk <= 8; msk <<= 1)
#pragma unroll
      for (int mt = 0; mt < 6; ++mt)
#pragma unroll
        for (int r = 0; r < 4; ++r) {
          sv[mt][r] += __shfl_xor(sv[mt][r], msk, 64);
          qv[mt][r] += __shfl_xor(qv[mt][r], msk, 64);
        }
    if (l15 == 0)
#pragma unroll
      for (int mt = 0; mt < 6; ++mt)
#pragma unroll
        for (int r = 0; r < 4; ++r) {
          int o = mt * 16 + kg * 4 + r;
          ssum[nt * 96 + o] = sv[mt][r];
          sqsum[nt * 96 + o] = qv[mt][r];
        }
    __syncthreads();
    if (t < 96) {
      float S = ssum[t] + ssum[96 + t] + ssum[192 + t] + ssum[288 + t];
      float Q = sqsum[t] + sqsum[96 + t] + sqsum[192 + t] + sqsum[288 + t];
      float* dst = st_out + (tile & (NREP - 1)) * 384 + b * 192 + t * 2;
      atomicAdd(dst + 0, S);
      atomicAdd(dst + 1, Q);
    }
  }
}

// ---------------- attention kernel A: sinkhorn + top3 cut (qm precomputed) --
__global__ __launch_bounds__(256) void attnA_k(const float* __restrict__ qmg,
                                               float* __restrict__ Pg) {
  int head = blockIdx.x;
  __shared__ float qm[160];
  __shared__ float L[110];
  int t = threadIdx.x;
  if (t < 160) qm[t] = qmg[head * 160 + t];
  __syncthreads();
  if (t < 100) {
    int m = t / 10, n2 = t % 10;
    float acc = 0.f;
#pragma unroll
    for (int j = 0; j < 16; ++j) acc += qm[m * 16 + j] * qm[n2 * 16 + j];
    L[m * 11 + n2] = acc * ITEMP;
  }
  __syncthreads();
  for (int it = 0; it < 8; ++it) {
    if (t < 10) {
      float mx = -3.4e38f;
      for (int n2 = 0; n2 < 10; ++n2) mx = fmaxf(mx, L[t * 11 + n2]);
      float s = 0.f;
      for (int n2 = 0; n2 < 10; ++n2) s += expf(L[t * 11 + n2] - mx);
      float lse = mx + logf(s);
      for (int n2 = 0; n2 < 10; ++n2) L[t * 11 + n2] -= lse;
    }
    __syncthreads();
    if (t < 10) {
      float mx = -3.4e38f;
      for (int m = 0; m < 10; ++m) mx = fmaxf(mx, L[m * 11 + t]);
      float s = 0.f;
      for (int m = 0; m < 10; ++m) s += expf(L[m * 11 + t] - mx);
      float lse = mx + logf(s);
      for (int m = 0; m < 10; ++m) L[m * 11 + t] -= lse;
    }
    __syncthreads();
  }
  if (t < 10) {
    float p[10];
#pragma unroll
    for (int n2 = 0; n2 < 10; ++n2) p[n2] = expf(L[t * 11 + n2]);
    int i1 = -1, i2 = -1;
    float m1 = -1.f, m2 = -1.f, m3 = -1.f;
#pragma unroll
    for (int n2 = 0; n2 < 10; ++n2) if (p[n2] > m1) { m1 = p[n2]; i1 = n2; }
#pragma unroll
    for (int n2 = 0; n2 < 10; ++n2) if (n2 != i1 && p[n2] > m2) { m2 = p[n2]; i2 = n2; }
#pragma unroll
    for (int n2 = 0; n2 < 10; ++n2) if (n2 != i1 && n2 != i2 && p[n2] > m3) m3 = p[n2];
#pragma unroll
    for (int n2 = 0; n2 < 10; ++n2)
      Pg[head * 100 + t * 10 + n2] = (p[n2] >= m3) ? p[n2] : 0.f;
  }
}

// ---------------- attention kernel B — MFMA, bf16 feat in -------------------
// MFMA core identical to R11 (verified). Inputs now bf16 featb (+ felub for
// elu): Q stage = straight u32 copies (bf16 pairs ARE the k-pair format),
// mix phase has no expf and half the load bytes.
__global__ __launch_bounds__(256) void attnB_k(
    const unsigned short* __restrict__ fbg, const unsigned short* __restrict__ feg,
    const float* __restrict__ Pg, float* __restrict__ out) {
  __shared__ __align__(16) unsigned Qs[112 * 20];   // [row][d-pairs], pitch 20
  __shared__ __align__(16) unsigned Ks[112 * 20];   // [key][d-pairs]
  __shared__ __align__(16) unsigned Vt[16 * 68];    // [d][key-pairs], pitch 68
  __shared__ __align__(16) unsigned P2[112 * 68];   // [row][key-pairs]
  int m = blockIdx.x % 10;
  int head = blockIdx.x / 10;
  int b = head / 576, rem = head % 576, c = rem / 6, grp = rem % 6;
  size_t fboff = (size_t)b * CNW + c * 96000 + grp * 16;
  const unsigned short* fbp = fbg + fboff;
  const unsigned short* fep = feg + fboff;
  int t = threadIdx.x;

  // zero pad regions
  for (int i = t; i < 896; i += 256) {          // Q,K d-pairs 8-15 (K 16->32)
    int row = i >> 3, cc = i & 7;
    Qs[row * 20 + 8 + cc] = 0;
    Ks[row * 20 + 8 + cc] = 0;
  }
  for (int i = t; i < 96; i += 256) {           // rows 100-111, d-pairs 0-7
    int row = 100 + (i >> 3), cc = i & 7;
    Qs[row * 20 + cc] = 0;
    Ks[row * 20 + cc] = 0;
  }
  for (int i = t; i < 224; i += 256) {          // V key-pairs 50-63
    int d = i / 14, cc = i % 14;
    Vt[d * 68 + 50 + cc] = 0;
  }
  for (int i = t; i < 896; i += 256) {          // P key-pairs 56-63
    int row = i >> 3, cc = i & 7;
    P2[row * 68 + 56 + cc] = 0;
  }

  float p[10];
#pragma unroll
  for (int n2 = 0; n2 < 10; ++n2) p[n2] = Pg[head * 100 + m * 10 + n2];

  // Q tile: bf16 pairs are already the k-pair format -> straight copies
  for (int i = t; i < 800; i += 256) {
    int s = i >> 3, p8 = i & 7;
    Qs[s * 20 + p8] = ((const unsigned*)(fbp + (size_t)(m * 100 + s) * 96))[p8];
  }
  // K',V' mix: unit (key-pair sp, quad q); elu precomputed in felub
  if (t < 200) {
    int sp = t >> 2, q = t & 3;
    float4 ak0 = make_float4(0.f, 0.f, 0.f, 0.f), ak1 = ak0, av0 = ak0, av1 = ak0;
#pragma unroll
    for (int n2 = 0; n2 < 10; ++n2) {
      if (p[n2] != 0.f) {
        float pe = p[n2];
        const unsigned* ka = (const unsigned*)(fbp + (size_t)(n2 * 100 + 2 * sp) * 96) + 2 * q;
        const unsigned* ea = (const unsigned*)(fep + (size_t)(n2 * 100 + 2 * sp) * 96) + 2 * q;
        unsigned ku0 = ka[0], ku1 = ka[1], ku2 = ka[48], ku3 = ka[49];
        unsigned eu0 = ea[0], eu1 = ea[1], eu2 = ea[48], eu3 = ea[49];
        ak0.x += pe * blo(ku0); ak0.y += pe * bhi(ku0);
        ak0.z += pe * blo(ku1); ak0.w += pe * bhi(ku1);
        ak1.x += pe * blo(ku2); ak1.y += pe * bhi(ku2);
        ak1.z += pe * blo(ku3); ak1.w += pe * bhi(ku3);
        av0.x += pe * blo(eu0); av0.y += pe * bhi(eu0);
        av0.z += pe * blo(eu1); av0.w += pe * bhi(eu1);
        av1.x += pe * blo(eu2); av1.y += pe * bhi(eu2);
        av1.z += pe * blo(eu3); av1.w += pe * bhi(eu3);
      }
    }
    Ks[(2 * sp) * 20 + 2 * q]         = bfr(ak0.x) | (bfr(ak0.y) << 16);
    Ks[(2 * sp) * 20 + 2 * q + 1]     = bfr(ak0.z) | (bfr(ak0.w) << 16);
    Ks[(2 * sp + 1) * 20 + 2 * q]     = bfr(ak1.x) | (bfr(ak1.y) << 16);
    Ks[(2 * sp + 1) * 20 + 2 * q + 1] = bfr(ak1.z) | (bfr(ak1.w) << 16);
    Vt[(4 * q + 0) * 68 + sp] = bfr(av0.x) | (bfr(av1.x) << 16);
    Vt[(4 * q + 1) * 68 + sp] = bfr(av0.y) | (bfr(av1.y) << 16);
    Vt[(4 * q + 2) * 68 + sp] = bfr(av0.z) | (bfr(av1.z) << 16);
    Vt[(4 * q + 3) * 68 + sp] = bfr(av0.w) | (bfr(av1.w) << 16);
  }
  __syncthreads();

  int lane = t & 63, w = t >> 6;
  int l15 = lane & 15, kg = lane >> 4;
  int nmt = (w < 3) ? 2 : 1;
  float rinv[2][4];
#pragma unroll
  for (int im = 0; im < 2; ++im) {
    if (im < nmt) {
      int mt = w * 2 + im;
      FragU qf;
      int qbase = (mt * 16 + l15) * 20 + kg * 4;
      qf.u[0] = Qs[qbase + 0]; qf.u[1] = Qs[qbase + 1];
      qf.u[2] = Qs[qbase + 2]; qf.u[3] = Qs[qbase + 3];
      f32x4 s[7];
#pragma unroll
      for (int nt2 = 0; nt2 < 7; ++nt2) {
        FragU kf;
        int kbase = (nt2 * 16 + l15) * 20 + kg * 4;
        kf.u[0] = Ks[kbase + 0]; kf.u[1] = Ks[kbase + 1];
        kf.u[2] = Ks[kbase + 2]; kf.u[3] = Ks[kbase + 3];
        s[nt2] = __builtin_amdgcn_mfma_f32_16x16x32_bf16(
            qf.v, kf.v, (f32x4){0.f, 0.f, 0.f, 0.f}, 0, 0, 0);
      }
      if (l15 >= 4) {
        s[6][0] = -3.0e38f; s[6][1] = -3.0e38f;
        s[6][2] = -3.0e38f; s[6][3] = -3.0e38f;
      }
#pragma unroll
      for (int r = 0; r < 4; ++r) {
        float mx = s[0][r];
#pragma unroll
        for (int nt2 = 1; nt2 < 7; ++nt2) mx = fmaxf(mx, s[nt2][r]);
        mx = fmaxf(mx, __shfl_xor(mx, 1, 64));
        mx = fmaxf(mx, __shfl_xor(mx, 2, 64));
        mx = fmaxf(mx, __shfl_xor(mx, 4, 64));
        mx = fmaxf(mx, __shfl_xor(mx, 8, 64));
        float pv[7];
        float sum = 0.f;
#pragma unroll
        for (int nt2 = 0; nt2 < 7; ++nt2) {
          pv[nt2] = __expf((s[nt2][r] - mx) * ITEMP);
          sum += pv[nt2];
        }
        sum += __shfl_xor(sum, 1, 64);
        sum += __shfl_xor(sum, 2, 64);
        sum += __shfl_xor(sum, 4, 64);
        sum += __shfl_xor(sum, 8, 64);
        rinv[im][r] = 1.f / sum;
        int row = mt * 16 + kg * 4 + r;
#pragma unroll
        for (int nt2 = 0; nt2 < 7; ++nt2) {
          float other = __shfl_xor(pv[nt2], 1, 64);
          if ((l15 & 1) == 0)
            P2[row * 68 + nt2 * 8 + (l15 >> 1)] = bfr(pv[nt2]) | (bfr(other) << 16);
        }
      }
    }
  }
  __syncthreads();
#pragma unroll
  for (int im = 0; im < 2; ++im) {
    if (im < nmt) {
      int mt = w * 2 + im;
      f32x4 acc = (f32x4){0.f, 0.f, 0.f, 0.f};
#pragma unroll
      for (int ks = 0; ks < 4; ++ks) {
        FragU pa, vb;
        int pbase = (mt * 16 + l15) * 68 + ks * 16 + kg * 4;
        pa.u[0] = P2[pbase + 0]; pa.u[1] = P2[pbase + 1];
        pa.u[2] = P2[pbase + 2]; pa.u[3] = P2[pbase + 3];
        int vbase = l15 * 68 + ks * 16 + kg * 4;
        vb.u[0] = Vt[vbase + 0]; vb.u[1] = Vt[vbase + 1];
        vb.u[2] = Vt[vbase + 2]; vb.u[3] = Vt[vbase + 3];
        acc = __builtin_amdgcn_mfma_f32_16x16x32_bf16(pa.v, vb.v, acc, 0, 0, 0);
      }
      float* obp = out + b * CNW + c * 96000 + grp * 16 + (m * 100) * 96 + l15;
#pragma unroll
      for (int r = 0; r < 4; ++r) {
        int row = mt * 16 + kg * 4 + r;
        if (row < 100) obp[row * 96] = acc[r] * rinv[im][r];
      }
    }
  }
}

// ------ t = swapaxes(feat_attn,1,3) + x, with fused GN stats ---------------
__global__ __launch_bounds__(256) void trans_add_k(const float* __restrict__ z,
    const float* __restrict__ x, float* __restrict__ out,
    float* __restrict__ rawGN) {
  __shared__ float ld[96 * 97];
  __shared__ float red[4 * 12];
  int b = blockIdx.x / 1000, n = blockIdx.x % 1000;
  int t = threadIdx.x;
  const float* zp = z + b * CNW + n * 96;
  for (int i = t; i < 9216; i += 256) {
    int r = i / 96, col = i % 96;
    ld[r * 97 + col] = zp[r * 96000 + col];
  }
  __syncthreads();
  const float* xp = x + b * CNW + n * 96;
  float* op = out + b * CNW + n * 96;
  float sg[6], qg[6];
#pragma unroll
  for (int g = 0; g < 6; ++g) { sg[g] = 0.f; qg[g] = 0.f; }
#pragma unroll
  for (int k = 0; k < 36; ++k) {
    int i = t + k * 256;
    int g = k / 6;                    // compile-time under unroll
    int cc = i / 96, ww = i % 96;
    float val = ld[ww * 97 + cc] + xp[cc * 96000 + ww];
    op[cc * 96000 + ww] = val;
    sg[g] += val;
    qg[g] += val * val;
  }
#pragma unroll
  for (int msk = 1; msk <= 32; msk <<= 1)
#pragma unroll
    for (int g = 0; g < 6; ++g) {
      sg[g] += __shfl_xor(sg[g], msk, 64);
      qg[g] += __shfl_xor(qg[g], msk, 64);
    }
  int wid = t >> 6;
  if ((t & 63) == 0)
#pragma unroll
    for (int g = 0; g < 6; ++g) {
      red[wid * 12 + g * 2 + 0] = sg[g];
      red[wid * 12 + g * 2 + 1] = qg[g];
    }
  __syncthreads();
  if (t < 12) {
    float s = red[t] + red[12 + t] + red[24 + t] + red[36 + t];
    atomicAdd(&rawGN[(n & (NREP - 1)) * 24 + b * 12 + t], s);
  }
}

// ---------------- out = relu( BN2(IN(l2)) + BNr(right_raw) ) -----------------
__global__ __launch_bounds__(256) void final_k(float* __restrict__ outp,
    const float* __restrict__ l2, const float* __restrict__ stR,
    const float* __restrict__ st2, const float* __restrict__ rw,
    const float* __restrict__ rb, const float* __restrict__ w2,
    const float* __restrict__ b2) {
  int stride = gridDim.x * 256;
  for (int i4 = blockIdx.x * 256 + threadIdx.x; i4 < 4608000; i4 += stride) {
    int i = i4 * 4;
    int b = i / CNW, o = (i / 96000) % 96;
    float mr = (stR[o * 2] + stR[192 + o * 2]) * (1.f / 192000.f);
    float vr = (stR[o * 2 + 1] + stR[192 + o * 2 + 1]) * (1.f / 192000.f) - mr * mr;
    float rs = rsqrtf(vr + EPSV) * rw[o];
    float rsh = rb[o] - mr * rs;
    const float inv = 1.f / 96000.f;
    float m0 = st2[o * 2] * inv,       v0 = st2[o * 2 + 1] * inv - m0 * m0;
    float m1 = st2[192 + o * 2] * inv, v1 = st2[192 + o * 2 + 1] * inv - m1 * m1;
    float bv = 0.5f * (v0 / (v0 + EPSV) + v1 / (v1 + EPSV));
    float ls = rsqrtf(bv + EPSV) * w2[o];
    float mi = b ? m1 : m0, vi = b ? v1 : v0;
    float lsc = rsqrtf(vi + EPSV) * ls;
    float lsh = b2[o] - mi * lsc;
    float4 R = ((float4*)outp)[i4];
    float4 L = ((const float4*)l2)[i4];
    float4 O;
    O.x = fmaxf(R.x * rs + rsh + L.x * lsc + lsh, 0.f);
    O.y = fmaxf(R.y * rs + rsh + L.y * lsc + lsh, 0.f);
    O.z = fmaxf(R.z * rs + rsh + L.z * lsc + lsh, 0.f);
    O.w = fmaxf(R.w * rs + rsh + L.w * lsc + lsh, 0.f);
    ((float4*)outp)[i4] = O;
  }
}

extern "C" void kernel_launch(void* const* d_in, const int* in_sizes, int n_in,
                              void* d_out, int out_size, void* d_ws, size_t ws_size,
                              hipStream_t stream) {
  const float* x        = (const float*)d_in[0];
  const float* w_linear = (const float*)d_in[1];
  const float* gn_w     = (const float*)d_in[2];
  const float* gn_b     = (const float*)d_in[3];
  const float* w_right  = (const float*)d_in[4];
  const float* b_right  = (const float*)d_in[5];
  const float* bn_r_w   = (const float*)d_in[6];
  const float* bn_r_b   = (const float*)d_in[7];
  const float* w_l1     = (const float*)d_in[8];
  const float* b_l1     = (const float*)d_in[9];
  const float* bn1_w    = (const float*)d_in[10];
  const float* bn1_b    = (const float*)d_in[11];
  const float* w_l2     = (const float*)d_in[12];
  const float* b_l2     = (const float*)d_in[13];
  const float* bn2_w    = (const float*)d_in[14];
  const float* bn2_b    = (const float*)d_in[15];
  float* out = (float*)d_out;

  float* A      = (float*)d_ws;            // TOT floats (featb+felub, later y/l2)
  unsigned short* featb = (unsigned short*)A;     // TOT ushorts
  unsigned short* felub = featb + TOT;            // TOT ushorts (= A+TOT floats end)
  float* Bb     = A + TOT;                 // TOT floats (attn out, later l1)
  float* Pg     = Bb + TOT;                // 115200
  float* rawGN  = Pg + 115200;             // NREP*24 = 384
  float* rawBNr = rawGN + NREP * 24;       // NREP*384
  float* rawIN1 = rawBNr + NREP * 384;     // NREP*384
  float* rawIN2 = rawIN1 + NREP * 384;     // NREP*384
  float* stBNr  = rawIN2 + NREP * 384;     // 384
  float* stIN2  = stBNr + 384;             // 384
  unsigned* w2_0  = (unsigned*)(stIN2 + 384);  // 4704
  unsigned* w2R   = w2_0 + 4704;               // 2*4704
  unsigned* w2L   = w2R + 2 * 4704;            // 2*4704
  unsigned* w2l2  = w2L + 2 * 4704;            // 4704
  float* b2R   = (float*)(w2l2 + 4704);        // 192
  float* b2L   = b2R + 192;                    // 192
  float* b2l2  = b2L + 192;                    // 192
  float* scl1g = b2l2 + 192;                   // 192
  float* shf1g = scl1g + 192;                  // 192
  float* xm    = shf1g + 192;                  // 184320
  float* qmg   = xm + 184320;                  // 184320

  hipMemsetAsync(rawGN, 0, (NREP * 24 + 3 * NREP * 384) * sizeof(float), stream);

  prep0_k<<<1, 256, 0, stream>>>(w_linear, w2_0);
  // feat (+elu) = conv1x1(x, w_linear) -> featb/felub (bf16, MFMA)
  convb0_k<<<3000, 256, 0, stream>>>(x, w2_0, featb, felub);
  // exact fp32 path for the sinkhorn cut: xm = mean_s(x), qm = W @ xm
  xmean_k<<<1920, 128, 0, stream>>>(x, xm);
  qm_k<<<20, 256, 0, stream>>>(xm, w_linear, qmg);
  attnA_k<<<1152, 256, 0, stream>>>(qmg, Pg);
  // attention -> Bb
  attnB_k<<<11520, 256, 0, stream>>>(featb, felub, Pg, Bb);
  // t = swapaxes(feat_attn,1,3) + x -> A (featb/felub dead); GN stats
  trans_add_k<<<2000, 256, 0, stream>>>(Bb, x, A, rawGN);
  prep_rl_k<<<1, 256, 0, stream>>>(rawGN, w_right, b_right, w_l1, b_l1,
                                   gn_w, gn_b, w2R, b2R, w2L, b2L);
  convm_k<1, 1><<<3000, 256, 0, stream>>>(A, w2R, b2R, nullptr, nullptr,
                                          out, rawBNr);
  convm_k<1, 1><<<3000, 256, 0, stream>>>(A, w2L, b2L, nullptr, nullptr,
                                          Bb, rawIN1);
  prep_l2_k<<<1, 256, 0, stream>>>(rawIN1, w_l2, b_l2, bn1_w, bn1_b,
                                   w2l2, b2l2, scl1g, shf1g);
  convm_k<2, 1><<<3000, 256, 0, stream>>>(Bb, w2l2, b2l2, scl1g, shf1g,
                                          A, rawIN2);
  collapse_k<<<3, 256, 0, stream>>>(rawBNr, stBNr, rawIN2, stIN2);
  final_k<<<2048, 256, 0, stream>>>(out, A, stBNr, stIN2,
                                    bn_r_w, bn_r_b, bn2_w, bn2_b);
}

// Round 13
// 570.976 us; speedup vs baseline: 1.0170x; 1.0170x over previous
//
#include <hip/hip_runtime.h>
#include <math.h>

#define CNW 9216000      // C*N*W = 96*1000*96
#define TOT 18432000     // B*C*N*W
#define EPSV 1e-5f
#define ITEMP 0.10206207261596575f   // 1/sqrt(96)
#define NREP 16          // stats replicas (breaks same-address atomic chains)

typedef __attribute__((ext_vector_type(8))) short bf16x8;   // 8 bf16 = 4 VGPR
typedef __attribute__((ext_vector_type(4))) float f32x4;

union FragU { unsigned u[4]; bf16x8 v; };

// round-to-nearest-even fp32 -> bf16 (upper 16 bits)
__device__ __forceinline__ unsigned bfr(float x) {
  union { float f; unsigned u; } v; v.f = x;
  return (v.u + 0x7fffu + ((v.u >> 16) & 1u)) >> 16;
}
__device__ __forceinline__ float eluf(float x) {
  return fmaxf(x, 0.f) + __expf(fminf(x, 0.f)) - 1.f;
}
// unpack bf16 pair (u32) -> fp32 (exact)
__device__ __forceinline__ float blo(unsigned u) {
  union { unsigned x; float f; } v; v.x = u << 16; return v.f;
}
__device__ __forceinline__ float bhi(unsigned u) {
  union { unsigned x; float f; } v; v.x = u & 0xffff0000u; return v.f;
}

// =============== prep: pack weights into bf16 k-pair layout =================
__global__ __launch_bounds__(256) void prep0_k(const float* __restrict__ w,
                                               unsigned* __restrict__ w2g) {
  int t = threadIdx.x;
  for (int i = t; i < 4704; i += 256) {
    int o = i / 49, c2 = i % 49;
    unsigned p = 0;
    if (c2 < 48) p = bfr(w[o * 96 + 2 * c2]) | (bfr(w[o * 96 + 2 * c2 + 1]) << 16);
    w2g[i] = p;
  }
}

// collapse GN replicas, fold GN scale into w_right/w_l1 (per b), exact bias2
__global__ __launch_bounds__(256) void prep_rl_k(const float* __restrict__ rawGN,
    const float* __restrict__ wR, const float* __restrict__ bR,
    const float* __restrict__ wL, const float* __restrict__ bL,
    const float* __restrict__ gnw, const float* __restrict__ gnb,
    unsigned* __restrict__ w2R, float* __restrict__ b2R,
    unsigned* __restrict__ w2L, float* __restrict__ b2L) {
  __shared__ float stGN[24];
  __shared__ float scl[2][96], sh[2][96];
  int t = threadIdx.x;
  if (t < 24) {
    float s = 0.f;
    for (int r = 0; r < NREP; ++r) s += rawGN[r * 24 + t];
    stGN[t] = s;
  }
  __syncthreads();
  if (t < 192) {
    int b = t / 96, c = t % 96, g = c >> 4;
    float m = stGN[b * 12 + g * 2] * (1.f / 1536000.f);
    float v = stGN[b * 12 + g * 2 + 1] * (1.f / 1536000.f) - m * m;
    float sc = rsqrtf(v + EPSV) * gnw[c];
    scl[b][c] = sc;
    sh[b][c] = gnb[c] - m * sc;
  }
  __syncthreads();
  for (int i = t; i < 2 * 2 * 4704; i += 256) {
    int wsel = i / 9408, rem = i % 9408, b = rem / 4704, j = rem % 4704;
    int o = j / 49, c2 = j % 49;
    const float* W = wsel ? wL : wR;
    unsigned p = 0;
    if (c2 < 48) {
      float w0 = W[o * 96 + 2 * c2] * scl[b][2 * c2];
      float w1 = W[o * 96 + 2 * c2 + 1] * scl[b][2 * c2 + 1];
      p = bfr(w0) | (bfr(w1) << 16);
    }
    (wsel ? w2L : w2R)[b * 4704 + j] = p;
  }
  for (int i = t; i < 2 * 2 * 96; i += 256) {
    int wsel = i / 192, rem = i % 192, b = rem / 96, o = rem % 96;
    const float* W = wsel ? wL : wR;
    float acc = (wsel ? bL : bR)[o];
    for (int c = 0; c < 96; ++c) acc += W[o * 96 + c] * sh[b][c];
    (wsel ? b2L : b2R)[b * 96 + o] = acc;
  }
}

// collapse IN1 replicas, compute BN1(IN) affine, pack w_l2 (unscaled)
__global__ __launch_bounds__(256) void prep_l2_k(const float* __restrict__ rawIN1,
    const float* __restrict__ w, const float* __restrict__ bi,
    const float* __restrict__ bn1w, const float* __restrict__ bn1b,
    unsigned* __restrict__ w2g, float* __restrict__ b2g,
    float* __restrict__ sclg, float* __restrict__ shfg) {
  __shared__ float st[384];
  int t = threadIdx.x;
  for (int i = t; i < 384; i += 256) {
    float s = 0.f;
    for (int r = 0; r < NREP; ++r) s += rawIN1[r * 384 + i];
    st[i] = s;
  }
  __syncthreads();
  if (t < 192) {
    int b = t / 96, c = t % 96;
    const float inv = 1.f / 96000.f;
    float m0 = st[c * 2] * inv, v0 = st[c * 2 + 1] * inv - m0 * m0;
    float m1 = st[192 + c * 2] * inv, v1 = st[192 + c * 2 + 1] * inv - m1 * m1;
    float bv = 0.5f * (v0 / (v0 + EPSV) + v1 / (v1 + EPSV));
    float bscale = rsqrtf(bv + EPSV) * bn1w[c];
    float mi = b ? m1 : m0, vi = b ? v1 : v0;
    float sc = rsqrtf(vi + EPSV) * bscale;
    sclg[t] = sc;
    shfg[t] = bn1b[c] - mi * sc;
    b2g[t] = bi[c];
  }
  for (int i = t; i < 4704; i += 256) {
    int o = i / 49, c2 = i % 49;
    unsigned p = 0;
    if (c2 < 48) p = bfr(w[o * 96 + 2 * c2]) | (bfr(w[o * 96 + 2 * c2 + 1]) << 16);
    w2g[i] = p;
  }
}

// =============== conv0 via MFMA: feat & elu(feat) in HEAD-MAJOR bf16 ========
// featH[head = b*576+c*6+g][s=0..999][d=0..15]; head slices are contiguous so
// attnB reads are dense (R12's [B,C,N,W] slice used 32B of each 64B line).
__global__ __launch_bounds__(256) void convb0_k(const float* __restrict__ xin,
    const unsigned* __restrict__ w2g,
    unsigned short* __restrict__ fb, unsigned short* __restrict__ fe) {
  __shared__ __align__(16) unsigned ldsW[96 * 49];
  __shared__ __align__(16) unsigned xt2[64 * 49];
  int tile = blockIdx.x % 1500, b = blockIdx.x / 1500;
  int nw0 = tile * 64;
  int t = threadIdx.x;
  for (int i = t; i < 1176; i += 256)
    ((float4*)ldsW)[i] = ((const float4*)w2g)[i];
  const float* xb = xin + b * CNW + nw0;
  for (int i = t; i < 768; i += 256) {
    int c2 = i >> 4, j4 = i & 15;
    const float* r0 = xb + (2 * c2) * 96000 + j4 * 4;
    float4 x0 = *(const float4*)r0;
    float4 x1 = *(const float4*)(r0 + 96000);
    int base = j4 * 4;
    xt2[(base + 0) * 49 + c2] = bfr(x0.x) | (bfr(x1.x) << 16);
    xt2[(base + 1) * 49 + c2] = bfr(x0.y) | (bfr(x1.y) << 16);
    xt2[(base + 2) * 49 + c2] = bfr(x0.z) | (bfr(x1.z) << 16);
    xt2[(base + 3) * 49 + c2] = bfr(x0.w) | (bfr(x1.w) << 16);
  }
  __syncthreads();
  int lane = t & 63, nt = t >> 6;
  int l15 = lane & 15, kg = lane >> 4;
  f32x4 acc[6];
#pragma unroll
  for (int mt = 0; mt < 6; ++mt) acc[mt] = (f32x4){0.f, 0.f, 0.f, 0.f};
#pragma unroll
  for (int ks = 0; ks < 3; ++ks) {
    int cb = ks * 16 + kg * 4;
    FragU bf;
    int brow = (nt * 16 + l15) * 49 + cb;
    bf.u[0] = xt2[brow + 0]; bf.u[1] = xt2[brow + 1];
    bf.u[2] = xt2[brow + 2]; bf.u[3] = xt2[brow + 3];
#pragma unroll
    for (int mt = 0; mt < 6; ++mt) {
      FragU af;
      int arow = (mt * 16 + l15) * 49 + cb;
      af.u[0] = ldsW[arow + 0]; af.u[1] = ldsW[arow + 1];
      af.u[2] = ldsW[arow + 2]; af.u[3] = ldsW[arow + 3];
      acc[mt] = __builtin_amdgcn_mfma_f32_16x16x32_bf16(af.v, bf.v, acc[mt], 0, 0, 0);
    }
  }
  // head-major epilogue: nwb 16-aligned => same n and same g for all 16 lanes
  int nwb = nw0 + nt * 16;
  int n = nwb / 96, w0 = nwb % 96, g = w0 >> 4;
  unsigned short* f1 = fb + (size_t)b * CNW + g * 16000 + n * 16 + l15;
  unsigned short* f2 = fe + (size_t)b * CNW + g * 16000 + n * 16 + l15;
#pragma unroll
  for (int mt = 0; mt < 6; ++mt)
#pragma unroll
    for (int r = 0; r < 4; ++r) {
      int o = mt * 16 + kg * 4 + r;
      float val = acc[mt][r];
      f1[o * 96000] = (unsigned short)bfr(val);
      f2[o * 96000] = (unsigned short)bfr(eluf(val));
    }
}

// =============== xmean: xm[b][m][cin][w] = mean_s x[b][cin][m*100+s][w] =====
__global__ __launch_bounds__(128) void xmean_k(const float* __restrict__ x,
                                               float* __restrict__ xm) {
  int cin = blockIdx.x % 96, bm = blockIdx.x / 96;   // bm = b*10+m
  int b = bm / 10, m = bm % 10;
  int t = threadIdx.x;
  if (t < 96) {
    const float* xp = x + (size_t)(b * 96 + cin) * 96000 + m * 100 * 96 + t;
    float s = 0.f;
    for (int r = 0; r < 100; ++r) s += xp[r * 96];
    xm[(bm * 96 + cin) * 96 + t] = s * 0.01f;
  }
}

// =============== qm: per (b,m) tiny GEMM W @ xm -> qmg[head][m][j] ==========
__global__ __launch_bounds__(256) void qm_k(const float* __restrict__ xm,
    const float* __restrict__ w, float* __restrict__ qmg) {
  __shared__ float Wl[96 * 97], Xl[96 * 97];
  int b = blockIdx.x / 10, m = blockIdx.x % 10;
  int t = threadIdx.x;
  for (int i = t; i < 9216; i += 256) {
    int r = i / 96, cc = i % 96;
    Wl[r * 97 + cc] = w[i];
    Xl[r * 97 + cc] = xm[((b * 10 + m) * 96 + r) * 96 + cc];
  }
  __syncthreads();
  for (int i = t; i < 9216; i += 256) {
    int c = i / 96, ww = i % 96;
    float acc = 0.f;
    for (int k = 0; k < 96; ++k) acc += Wl[c * 97 + k] * Xl[k * 97 + ww];
    int g = ww >> 4, j = ww & 15;
    qmg[(b * 576 + c * 6 + g) * 160 + m * 16 + j] = acc;
  }
}

// ---------------- collapse NREP replicas -> canonical [384] -----------------
__global__ __launch_bounds__(256) void collapse_k(const float* __restrict__ r0,
    float* __restrict__ o0, const float* __restrict__ r1, float* __restrict__ o1) {
  int t = blockIdx.x * 256 + threadIdx.x;
  const float* r = (t < 384) ? r0 : r1;
  float* o = (t < 384) ? o0 : o1;
  int i = (t < 384) ? t : t - 384;
  if (t < 768 && r) {
    float s = 0.f;
#pragma unroll
    for (int k = 0; k < NREP; ++k) s += r[k * 384 + i];
    o[i] = s;
  }
}

// =============== MFMA conv: D[o,nw] = W[96x96] @ X[96x96000] per batch ======
template <int MODE, int STATS>
__global__ __launch_bounds__(256) void convm_k(const float* __restrict__ xin,
    const unsigned* __restrict__ w2g, const float* __restrict__ b2g,
    const float* __restrict__ sclg, const float* __restrict__ shfg,
    float* __restrict__ outp, float* __restrict__ st_out) {
  __shared__ __align__(16) unsigned ldsW[96 * 49];
  __shared__ __align__(16) unsigned xt2[64 * 49];
  __shared__ float ldsB[96], lS[96], lH[96];
  __shared__ float ssum[4 * 96], sqsum[4 * 96];
  int tile = blockIdx.x % 1500, b = blockIdx.x / 1500;
  int nw0 = tile * 64;
  int t = threadIdx.x;
  const unsigned* wsrc = w2g + (MODE == 1 ? b * 4704 : 0);
  for (int i = t; i < 1176; i += 256)
    ((float4*)ldsW)[i] = ((const float4*)wsrc)[i];
  if (t < 96) {
    ldsB[t] = (MODE == 0) ? 0.f : b2g[b * 96 + t];
    if (MODE == 2) { lS[t] = sclg[b * 96 + t]; lH[t] = shfg[b * 96 + t]; }
  }
  __syncthreads();
  const float* xb = xin + b * CNW + nw0;
  for (int i = t; i < 768; i += 256) {
    int c2 = i >> 4, j4 = i & 15;
    const float* r0 = xb + (2 * c2) * 96000 + j4 * 4;
    float4 x0 = *(const float4*)r0;
    float4 x1 = *(const float4*)(r0 + 96000);
    if (MODE == 2) {
      float s0 = lS[2 * c2], h0 = lH[2 * c2];
      float s1 = lS[2 * c2 + 1], h1 = lH[2 * c2 + 1];
      x0.x = fmaxf(x0.x * s0 + h0, 0.f); x0.y = fmaxf(x0.y * s0 + h0, 0.f);
      x0.z = fmaxf(x0.z * s0 + h0, 0.f); x0.w = fmaxf(x0.w * s0 + h0, 0.f);
      x1.x = fmaxf(x1.x * s1 + h1, 0.f); x1.y = fmaxf(x1.y * s1 + h1, 0.f);
      x1.z = fmaxf(x1.z * s1 + h1, 0.f); x1.w = fmaxf(x1.w * s1 + h1, 0.f);
    }
    int base = j4 * 4;
    xt2[(base + 0) * 49 + c2] = bfr(x0.x) | (bfr(x1.x) << 16);
    xt2[(base + 1) * 49 + c2] = bfr(x0.y) | (bfr(x1.y) << 16);
    xt2[(base + 2) * 49 + c2] = bfr(x0.z) | (bfr(x1.z) << 16);
    xt2[(base + 3) * 49 + c2] = bfr(x0.w) | (bfr(x1.w) << 16);
  }
  __syncthreads();
  int lane = t & 63, nt = t >> 6;
  int l15 = lane & 15, kg = lane >> 4;
  f32x4 acc[6];
#pragma unroll
  for (int mt = 0; mt < 6; ++mt) acc[mt] = (f32x4){0.f, 0.f, 0.f, 0.f};
#pragma unroll
  for (int ks = 0; ks < 3; ++ks) {
    int cb = ks * 16 + kg * 4;
    FragU bf;
    int brow = (nt * 16 + l15) * 49 + cb;
    bf.u[0] = xt2[brow + 0]; bf.u[1] = xt2[brow + 1];
    bf.u[2] = xt2[brow + 2]; bf.u[3] = xt2[brow + 3];
#pragma unroll
    for (int mt = 0; mt < 6; ++mt) {
      FragU af;
      int arow = (mt * 16 + l15) * 49 + cb;
      af.u[0] = ldsW[arow + 0]; af.u[1] = ldsW[arow + 1];
      af.u[2] = ldsW[arow + 2]; af.u[3] = ldsW[arow + 3];
      acc[mt] = __builtin_amdgcn_mfma_f32_16x16x32_bf16(af.v, bf.v, acc[mt], 0, 0, 0);
    }
  }
  float* ob = outp + b * CNW + nw0 + nt * 16 + l15;
  float sv[6][4], qv[6][4];
#pragma unroll
  for (int mt = 0; mt < 6; ++mt)
#pragma unroll
    for (int r = 0; r < 4; ++r) {
      int o = mt * 16 + kg * 4 + r;
      float val = acc[mt][r] + ldsB[o];
      ob[o * 96000] = val;
      if (STATS) { sv[mt][r] = val; qv[mt][r] = val * val; }
    }
  if (STATS) {
#pragma unroll
    for (int msk = 1; msk <= 8; msk <<= 1)
#pragma unroll
      for (int mt = 0; mt < 6; ++mt)
#pragma unroll
        for (int r = 0; r < 4; ++r) {
          sv[mt][r] += __shfl_xor(sv[mt][r], msk, 64);
          qv[mt][r] += __shfl_xor(qv[mt][r], msk, 64);
        }
    if (l15 == 0)
#pragma unroll
      for (int mt = 0; mt < 6; ++mt)
#pragma unroll
        for (int r = 0; r < 4; ++r) {
          int o = mt * 16 + kg * 4 + r;
          ssum[nt * 96 + o] = sv[mt][r];
          sqsum[nt * 96 + o] = qv[mt][r];
        }
    __syncthreads();
    if (t < 96) {
      float S = ssum[t] + ssum[96 + t] + ssum[192 + t] + ssum[288 + t];
      float Q = sqsum[t] + sqsum[96 + t] + sqsum[192 + t] + sqsum[288 + t];
      float* dst = st_out + (tile & (NREP - 1)) * 384 + b * 192 + t * 2;
      atomicAdd(dst + 0, S);
      atomicAdd(dst + 1, Q);
    }
  }
}

// ---------------- attention kernel A: sinkhorn + top3 cut (qm precomputed) --
__global__ __launch_bounds__(256) void attnA_k(const float* __restrict__ qmg,
                                               float* __restrict__ Pg) {
  int head = blockIdx.x;
  __shared__ float qm[160];
  __shared__ float L[110];
  int t = threadIdx.x;
  if (t < 160) qm[t] = qmg[head * 160 + t];
  __syncthreads();
  if (t < 100) {
    int m = t / 10, n2 = t % 10;
    float acc = 0.f;
#pragma unroll
    for (int j = 0; j < 16; ++j) acc += qm[m * 16 + j] * qm[n2 * 16 + j];
    L[m * 11 + n2] = acc * ITEMP;
  }
  __syncthreads();
  for (int it = 0; it < 8; ++it) {
    if (t < 10) {
      float mx = -3.4e38f;
      for (int n2 = 0; n2 < 10; ++n2) mx = fmaxf(mx, L[t * 11 + n2]);
      float s = 0.f;
      for (int n2 = 0; n2 < 10; ++n2) s += expf(L[t * 11 + n2] - mx);
      float lse = mx + logf(s);
      for (int n2 = 0; n2 < 10; ++n2) L[t * 11 + n2] -= lse;
    }
    __syncthreads();
    if (t < 10) {
      float mx = -3.4e38f;
      for (int m = 0; m < 10; ++m) mx = fmaxf(mx, L[m * 11 + t]);
      float s = 0.f;
      for (int m = 0; m < 10; ++m) s += expf(L[m * 11 + t] - mx);
      float lse = mx + logf(s);
      for (int m = 0; m < 10; ++m) L[m * 11 + t] -= lse;
    }
    __syncthreads();
  }
  if (t < 10) {
    float p[10];
#pragma unroll
    for (int n2 = 0; n2 < 10; ++n2) p[n2] = expf(L[t * 11 + n2]);
    int i1 = -1, i2 = -1;
    float m1 = -1.f, m2 = -1.f, m3 = -1.f;
#pragma unroll
    for (int n2 = 0; n2 < 10; ++n2) if (p[n2] > m1) { m1 = p[n2]; i1 = n2; }
#pragma unroll
    for (int n2 = 0; n2 < 10; ++n2) if (n2 != i1 && p[n2] > m2) { m2 = p[n2]; i2 = n2; }
#pragma unroll
    for (int n2 = 0; n2 < 10; ++n2) if (n2 != i1 && n2 != i2 && p[n2] > m3) m3 = p[n2];
#pragma unroll
    for (int n2 = 0; n2 < 10; ++n2)
      Pg[head * 100 + t * 10 + n2] = (p[n2] >= m3) ? p[n2] : 0.f;
  }
}

// ---------------- attention kernel B — MFMA, head-major bf16, LDS union -----
// 4 phases: A stage (Qs,Ks,Vt) | B QK^T -> regs | C softmax + P2 (P2 unions
// over Qs/Ks after barrier) | D PV. Pitches 21/69 (odd -> <=2-way banks).
// LDS 35328B -> 4 blocks/CU (was 52736 -> 3).
__global__ __launch_bounds__(256) void attnB_k(
    const unsigned short* __restrict__ fbg, const unsigned short* __restrict__ feg,
    const float* __restrict__ Pg, float* __restrict__ out) {
  __shared__ __align__(16) unsigned U[7728 + 1104];
  unsigned* P2 = U;            // [112][69] (phases C,D)
  unsigned* Qs = U;            // [112][21] (phases A,B; dead before P2 write)
  unsigned* Ks = U + 2352;     // [112][21]
  unsigned* Vt = U + 7728;     // [16][69]
  int m = blockIdx.x % 10;
  int head = blockIdx.x / 10;
  int b = head / 576, rem = head % 576, c = rem / 6, grp = rem % 6;
  const unsigned* fbH = (const unsigned*)fbg + (size_t)head * 8000;
  const unsigned* feH = (const unsigned*)feg + (size_t)head * 8000;
  int t = threadIdx.x;

  // ---- phase A: stage Q, mixed K', V' (+ zero pads) ----
  for (int i = t; i < 896; i += 256) {          // d-pairs 8-15 (K 16->32 pad)
    int row = i >> 3, cc = i & 7;
    Qs[row * 21 + 8 + cc] = 0;
    Ks[row * 21 + 8 + cc] = 0;
  }
  for (int i = t; i < 96; i += 256) {           // rows 100-111, d-pairs 0-7
    int row = 100 + (i >> 3), cc = i & 7;
    Qs[row * 21 + cc] = 0;
    Ks[row * 21 + cc] = 0;
  }
  for (int i = t; i < 224; i += 256) {          // V key-pairs 50-63
    int d = i / 14, cc = i % 14;
    Vt[d * 69 + 50 + cc] = 0;
  }
  float p[10];
#pragma unroll
  for (int n2 = 0; n2 < 10; ++n2) p[n2] = Pg[head * 100 + m * 10 + n2];
  // Q: dense head-major copies (bf16 pairs ARE the k-pair format)
  for (int i = t; i < 800; i += 256) {
    int s = i >> 3, p8 = i & 7;
    Qs[s * 21 + p8] = fbH[(m * 100 + s) * 8 + p8];
  }
  // K',V' mix: thread (sp,q); dense uint2 loads from head-major buffers
  if (t < 200) {
    int sp = t >> 2, q = t & 3;
    float4 ak0 = make_float4(0.f, 0.f, 0.f, 0.f), ak1 = ak0, av0 = ak0, av1 = ak0;
#pragma unroll
    for (int n2 = 0; n2 < 10; ++n2) {
      if (p[n2] != 0.f) {
        float pe = p[n2];
        int rbase = (n2 * 100 + 2 * sp) * 8 + 2 * q;
        uint2 k01 = *(const uint2*)(fbH + rbase);
        uint2 k23 = *(const uint2*)(fbH + rbase + 8);
        uint2 e01 = *(const uint2*)(feH + rbase);
        uint2 e23 = *(const uint2*)(feH + rbase + 8);
        ak0.x += pe * blo(k01.x); ak0.y += pe * bhi(k01.x);
        ak0.z += pe * blo(k01.y); ak0.w += pe * bhi(k01.y);
        ak1.x += pe * blo(k23.x); ak1.y += pe * bhi(k23.x);
        ak1.z += pe * blo(k23.y); ak1.w += pe * bhi(k23.y);
        av0.x += pe * blo(e01.x); av0.y += pe * bhi(e01.x);
        av0.z += pe * blo(e01.y); av0.w += pe * bhi(e01.y);
        av1.x += pe * blo(e23.x); av1.y += pe * bhi(e23.x);
        av1.z += pe * blo(e23.y); av1.w += pe * bhi(e23.y);
      }
    }
    Ks[(2 * sp) * 21 + 2 * q]         = bfr(ak0.x) | (bfr(ak0.y) << 16);
    Ks[(2 * sp) * 21 + 2 * q + 1]     = bfr(ak0.z) | (bfr(ak0.w) << 16);
    Ks[(2 * sp + 1) * 21 + 2 * q]     = bfr(ak1.x) | (bfr(ak1.y) << 16);
    Ks[(2 * sp + 1) * 21 + 2 * q + 1] = bfr(ak1.z) | (bfr(ak1.w) << 16);
    Vt[(4 * q + 0) * 69 + sp] = bfr(av0.x) | (bfr(av1.x) << 16);
    Vt[(4 * q + 1) * 69 + sp] = bfr(av0.y) | (bfr(av1.y) << 16);
    Vt[(4 * q + 2) * 69 + sp] = bfr(av0.z) | (bfr(av1.z) << 16);
    Vt[(4 * q + 3) * 69 + sp] = bfr(av0.w) | (bfr(av1.w) << 16);
  }
  __syncthreads();

  // ---- phase B: QK^T into registers (S-tiles live across the barrier) ----
  int lane = t & 63, w = t >> 6;
  int l15 = lane & 15, kg = lane >> 4;
  int nmt = (w < 3) ? 2 : 1;
  f32x4 s2[2][7];
#pragma unroll
  for (int im = 0; im < 2; ++im) {
    if (im < nmt) {
      int mt = w * 2 + im;
      FragU qf;
      int qbase = (mt * 16 + l15) * 21 + kg * 4;
      qf.u[0] = Qs[qbase + 0]; qf.u[1] = Qs[qbase + 1];
      qf.u[2] = Qs[qbase + 2]; qf.u[3] = Qs[qbase + 3];
#pragma unroll
      for (int nt2 = 0; nt2 < 7; ++nt2) {
        FragU kf;
        int kbase = (nt2 * 16 + l15) * 21 + kg * 4;
        kf.u[0] = Ks[kbase + 0]; kf.u[1] = Ks[kbase + 1];
        kf.u[2] = Ks[kbase + 2]; kf.u[3] = Ks[kbase + 3];
        s2[im][nt2] = __builtin_amdgcn_mfma_f32_16x16x32_bf16(
            qf.v, kf.v, (f32x4){0.f, 0.f, 0.f, 0.f}, 0, 0, 0);
      }
    }
  }
  __syncthreads();     // all Qs/Ks reads complete; P2 may alias them now

  // ---- phase C: softmax + P2 write ----
  for (int i = t; i < 896; i += 256) {          // P2 pad key-pairs 56-63
    int row = i >> 3, cc = i & 7;
    P2[row * 69 + 56 + cc] = 0;
  }
  float rinv[2][4];
#pragma unroll
  for (int im = 0; im < 2; ++im) {
    if (im < nmt) {
      int mt = w * 2 + im;
      if (l15 >= 4) {   // mask pad key-columns 100-111 (tile 6)
        s2[im][6][0] = -3.0e38f; s2[im][6][1] = -3.0e38f;
        s2[im][6][2] = -3.0e38f; s2[im][6][3] = -3.0e38f;
      }
#pragma unroll
      for (int r = 0; r < 4; ++r) {
        float mx = s2[im][0][r];
#pragma unroll
        for (int nt2 = 1; nt2 < 7; ++nt2) mx = fmaxf(mx, s2[im][nt2][r]);
        mx = fmaxf(mx, __shfl_xor(mx, 1, 64));
        mx = fmaxf(mx, __shfl_xor(mx, 2, 64));
        mx = fmaxf(mx, __shfl_xor(mx, 4, 64));
        mx = fmaxf(mx, __shfl_xor(mx, 8, 64));
        float pv[7];
        float sum = 0.f;
#pragma unroll
        for (int nt2 = 0; nt2 < 7; ++nt2) {
          pv[nt2] = __expf((s2[im][nt2][r] - mx) * ITEMP);
          sum += pv[nt2];
        }
        sum += __shfl_xor(sum, 1, 64);
        sum += __shfl_xor(sum, 2, 64);
        sum += __shfl_xor(sum, 4, 64);
        sum += __shfl_xor(sum, 8, 64);
        rinv[im][r] = 1.f / sum;
        int row = mt * 16 + kg * 4 + r;
#pragma unroll
        for (int nt2 = 0; nt2 < 7; ++nt2) {
          float other = __shfl_xor(pv[nt2], 1, 64);
          if ((l15 & 1) == 0)
            P2[row * 69 + nt2 * 8 + (l15 >> 1)] = bfr(pv[nt2]) | (bfr(other) << 16);
        }
      }
    }
  }
  __syncthreads();

  // ---- phase D: PV ----
#pragma unroll
  for (int im = 0; im < 2; ++im) {
    if (im < nmt) {
      int mt = w * 2 + im;
      f32x4 acc = (f32x4){0.f, 0.f, 0.f, 0.f};
#pragma unroll
      for (int ks = 0; ks < 4; ++ks) {
        FragU pa, vb;
        int pbase = (mt * 16 + l15) * 69 + ks * 16 + kg * 4;
        pa.u[0] = P2[pbase + 0]; pa.u[1] = P2[pbase + 1];
        pa.u[2] = P2[pbase + 2]; pa.u[3] = P2[pbase + 3];
        int vbase = l15 * 69 + ks * 16 + kg * 4;
        vb.u[0] = Vt[vbase + 0]; vb.u[1] = Vt[vbase + 1];
        vb.u[2] = Vt[vbase + 2]; vb.u[3] = Vt[vbase + 3];
        acc = __builtin_amdgcn_mfma_f32_16x16x32_bf16(pa.v, vb.v, acc, 0, 0, 0);
      }
      float* obp = out + b * CNW + c * 96000 + grp * 16 + (m * 100) * 96 + l15;
#pragma unroll
      for (int r = 0; r < 4; ++r) {
        int row = mt * 16 + kg * 4 + r;
        if (row < 100) obp[row * 96] = acc[r] * rinv[im][r];
      }
    }
  }
}

// ------ t = swapaxes(feat_attn,1,3) + x, with fused GN stats ---------------
__global__ __launch_bounds__(256) void trans_add_k(const float* __restrict__ z,
    const float* __restrict__ x, float* __restrict__ out,
    float* __restrict__ rawGN) {
  __shared__ float ld[96 * 97];
  __shared__ float red[4 * 12];
  int b = blockIdx.x / 1000, n = blockIdx.x % 1000;
  int t = threadIdx.x;
  const float* zp = z + b * CNW + n * 96;
  for (int i = t; i < 9216; i += 256) {
    int r = i / 96, col = i % 96;
    ld[r * 97 + col] = zp[r * 96000 + col];
  }
  __syncthreads();
  const float* xp = x + b * CNW + n * 96;
  float* op = out + b * CNW + n * 96;
  float sg[6], qg[6];
#pragma unroll
  for (int g = 0; g < 6; ++g) { sg[g] = 0.f; qg[g] = 0.f; }
#pragma unroll
  for (int k = 0; k < 36; ++k) {
    int i = t + k * 256;
    int g = k / 6;                    // compile-time under unroll
    int cc = i / 96, ww = i % 96;
    float val = ld[ww * 97 + cc] + xp[cc * 96000 + ww];
    op[cc * 96000 + ww] = val;
    sg[g] += val;
    qg[g] += val * val;
  }
#pragma unroll
  for (int msk = 1; msk <= 32; msk <<= 1)
#pragma unroll
    for (int g = 0; g < 6; ++g) {
      sg[g] += __shfl_xor(sg[g], msk, 64);
      qg[g] += __shfl_xor(qg[g], msk, 64);
    }
  int wid = t >> 6;
  if ((t & 63) == 0)
#pragma unroll
    for (int g = 0; g < 6; ++g) {
      red[wid * 12 + g * 2 + 0] = sg[g];
      red[wid * 12 + g * 2 + 1] = qg[g];
    }
  __syncthreads();
  if (t < 12) {
    float s = red[t] + red[12 + t] + red[24 + t] + red[36 + t];
    atomicAdd(&rawGN[(n & (NREP - 1)) * 24 + b * 12 + t], s);
  }
}

// ---------------- out = relu( BN2(IN(l2)) + BNr(right_raw) ) -----------------
__global__ __launch_bounds__(256) void final_k(float* __restrict__ outp,
    const float* __restrict__ l2, const float* __restrict__ stR,
    const float* __restrict__ st2, const float* __restrict__ rw,
    const float* __restrict__ rb, const float* __restrict__ w2,
    const float* __restrict__ b2) {
  int stride = gridDim.x * 256;
  for (int i4 = blockIdx.x * 256 + threadIdx.x; i4 < 4608000; i4 += stride) {
    int i = i4 * 4;
    int b = i / CNW, o = (i / 96000) % 96;
    float mr = (stR[o * 2] + stR[192 + o * 2]) * (1.f / 192000.f);
    float vr = (stR[o * 2 + 1] + stR[192 + o * 2 + 1]) * (1.f / 192000.f) - mr * mr;
    float rs = rsqrtf(vr + EPSV) * rw[o];
    float rsh = rb[o] - mr * rs;
    const float inv = 1.f / 96000.f;
    float m0 = st2[o * 2] * inv,       v0 = st2[o * 2 + 1] * inv - m0 * m0;
    float m1 = st2[192 + o * 2] * inv, v1 = st2[192 + o * 2 + 1] * inv - m1 * m1;
    float bv = 0.5f * (v0 / (v0 + EPSV) + v1 / (v1 + EPSV));
    float ls = rsqrtf(bv + EPSV) * w2[o];
    float mi = b ? m1 : m0, vi = b ? v1 : v0;
    float lsc = rsqrtf(vi + EPSV) * ls;
    float lsh = b2[o] - mi * lsc;
    float4 R = ((float4*)outp)[i4];
    float4 L = ((const float4*)l2)[i4];
    float4 O;
    O.x = fmaxf(R.x * rs + rsh + L.x * lsc + lsh, 0.f);
    O.y = fmaxf(R.y * rs + rsh + L.y * lsc + lsh, 0.f);
    O.z = fmaxf(R.z * rs + rsh + L.z * lsc + lsh, 0.f);
    O.w = fmaxf(R.w * rs + rsh + L.w * lsc + lsh, 0.f);
    ((float4*)outp)[i4] = O;
  }
}

extern "C" void kernel_launch(void* const* d_in, const int* in_sizes, int n_in,
                              void* d_out, int out_size, void* d_ws, size_t ws_size,
                              hipStream_t stream) {
  const float* x        = (const float*)d_in[0];
  const float* w_linear = (const float*)d_in[1];
  const float* gn_w     = (const float*)d_in[2];
  const float* gn_b     = (const float*)d_in[3];
  const float* w_right  = (const float*)d_in[4];
  const float* b_right  = (const float*)d_in[5];
  const float* bn_r_w   = (const float*)d_in[6];
  const float* bn_r_b   = (const float*)d_in[7];
  const float* w_l1     = (const float*)d_in[8];
  const float* b_l1     = (const float*)d_in[9];
  const float* bn1_w    = (const float*)d_in[10];
  const float* bn1_b    = (const float*)d_in[11];
  const float* w_l2     = (const float*)d_in[12];
  const float* b_l2     = (const float*)d_in[13];
  const float* bn2_w    = (const float*)d_in[14];
  const float* bn2_b    = (const float*)d_in[15];
  float* out = (float*)d_out;

  float* A      = (float*)d_ws;            // TOT floats (featb+felub, later y/l2)
  unsigned short* featb = (unsigned short*)A;     // TOT ushorts (head-major)
  unsigned short* felub = featb + TOT;            // TOT ushorts (head-major)
  float* Bb     = A + TOT;                 // TOT floats (attn out, later l1)
  float* Pg     = Bb + TOT;                // 115200
  float* rawGN  = Pg + 115200;             // NREP*24 = 384
  float* rawBNr = rawGN + NREP * 24;       // NREP*384
  float* rawIN1 = rawBNr + NREP * 384;     // NREP*384
  float* rawIN2 = rawIN1 + NREP * 384;     // NREP*384
  float* stBNr  = rawIN2 + NREP * 384;     // 384
  float* stIN2  = stBNr + 384;             // 384
  unsigned* w2_0  = (unsigned*)(stIN2 + 384);  // 4704
  unsigned* w2R   = w2_0 + 4704;               // 2*4704
  unsigned* w2L   = w2R + 2 * 4704;            // 2*4704
  unsigned* w2l2  = w2L + 2 * 4704;            // 4704
  float* b2R   = (float*)(w2l2 + 4704);        // 192
  float* b2L   = b2R + 192;                    // 192
  float* b2l2  = b2L + 192;                    // 192
  float* scl1g = b2l2 + 192;                   // 192
  float* shf1g = scl1g + 192;                  // 192
  float* xm    = shf1g + 192;                  // 184320
  float* qmg   = xm + 184320;                  // 184320

  hipMemsetAsync(rawGN, 0, (NREP * 24 + 3 * NREP * 384) * sizeof(float), stream);

  prep0_k<<<1, 256, 0, stream>>>(w_linear, w2_0);
  // feat (+elu) = conv1x1(x, w_linear) -> featb/felub (head-major bf16, MFMA)
  convb0_k<<<3000, 256, 0, stream>>>(x, w2_0, featb, felub);
  // exact fp32 path for the sinkhorn cut: xm = mean_s(x), qm = W @ xm
  xmean_k<<<1920, 128, 0, stream>>>(x, xm);
  qm_k<<<20, 256, 0, stream>>>(xm, w_linear, qmg);
  attnA_k<<<1152, 256, 0, stream>>>(qmg, Pg);
  // attention -> Bb
  attnB_k<<<11520, 256, 0, stream>>>(featb, felub, Pg, Bb);
  // t = swapaxes(feat_attn,1,3) + x -> A (featb/felub dead); GN stats
  trans_add_k<<<2000, 256, 0, stream>>>(Bb, x, A, rawGN);
  prep_rl_k<<<1, 256, 0, stream>>>(rawGN, w_right, b_right, w_l1, b_l1,
                                   gn_w, gn_b, w2R, b2R, w2L, b2L);
  convm_k<1, 1><<<3000, 256, 0, stream>>>(A, w2R, b2R, nullptr, nullptr,
                                          out, rawBNr);
  convm_k<1, 1><<<3000, 256, 0, stream>>>(A, w2L, b2L, nullptr, nullptr,
                                          Bb, rawIN1);
  prep_l2_k<<<1, 256, 0, stream>>>(rawIN1, w_l2, b_l2, bn1_w, bn1_b,
                                   w2l2, b2l2, scl1g, shf1g);
  convm_k<2, 1><<<3000, 256, 0, stream>>>(Bb, w2l2, b2l2, scl1g, shf1g,
                                          A, rawIN2);
  collapse_k<<<3, 256, 0, stream>>>(rawBNr, stBNr, rawIN2, stIN2);
  final_k<<<2048, 256, 0, stream>>>(out, A, stBNr, stIN2,
                                    bn_r_w, bn_r_b, bn2_w, bn2_b);
}

// Round 14
// 547.351 us; speedup vs baseline: 1.0609x; 1.0432x over previous
//
#include <hip/hip_runtime.h>
#include <math.h>

#define CNW 9216000      // C*N*W = 96*1000*96
#define TOT 18432000     // B*C*N*W
#define EPSV 1e-5f
#define ITEMP 0.10206207261596575f   // 1/sqrt(96)
#define NREP 16          // stats replicas (breaks same-address atomic chains)

typedef __attribute__((ext_vector_type(8))) short bf16x8;   // 8 bf16 = 4 VGPR
typedef __attribute__((ext_vector_type(4))) float f32x4;

union FragU { unsigned u[4]; bf16x8 v; };

// round-to-nearest-even fp32 -> bf16 (upper 16 bits)
__device__ __forceinline__ unsigned bfr(float x) {
  union { float f; unsigned u; } v; v.f = x;
  return (v.u + 0x7fffu + ((v.u >> 16) & 1u)) >> 16;
}
__device__ __forceinline__ float eluf(float x) {
  return fmaxf(x, 0.f) + __expf(fminf(x, 0.f)) - 1.f;
}
// unpack bf16 pair (u32) -> fp32 (exact)
__device__ __forceinline__ float blo(unsigned u) {
  union { unsigned x; float f; } v; v.x = u << 16; return v.f;
}
__device__ __forceinline__ float bhi(unsigned u) {
  union { unsigned x; float f; } v; v.x = u & 0xffff0000u; return v.f;
}

// =============== prep: pack weights into bf16 k-pair layout =================
__global__ __launch_bounds__(256) void prep0_k(const float* __restrict__ w,
                                               unsigned* __restrict__ w2g) {
  int t = threadIdx.x;
  for (int i = t; i < 4704; i += 256) {
    int o = i / 49, c2 = i % 49;
    unsigned p = 0;
    if (c2 < 48) p = bfr(w[o * 96 + 2 * c2]) | (bfr(w[o * 96 + 2 * c2 + 1]) << 16);
    w2g[i] = p;
  }
}

// collapse GN replicas, fold GN scale into w_right/w_l1 (per b), exact bias2
__global__ __launch_bounds__(256) void prep_rl_k(const float* __restrict__ rawGN,
    const float* __restrict__ wR, const float* __restrict__ bR,
    const float* __restrict__ wL, const float* __restrict__ bL,
    const float* __restrict__ gnw, const float* __restrict__ gnb,
    unsigned* __restrict__ w2R, float* __restrict__ b2R,
    unsigned* __restrict__ w2L, float* __restrict__ b2L) {
  __shared__ float stGN[24];
  __shared__ float scl[2][96], sh[2][96];
  int t = threadIdx.x;
  if (t < 24) {
    float s = 0.f;
    for (int r = 0; r < NREP; ++r) s += rawGN[r * 24 + t];
    stGN[t] = s;
  }
  __syncthreads();
  if (t < 192) {
    int b = t / 96, c = t % 96, g = c >> 4;
    float m = stGN[b * 12 + g * 2] * (1.f / 1536000.f);
    float v = stGN[b * 12 + g * 2 + 1] * (1.f / 1536000.f) - m * m;
    float sc = rsqrtf(v + EPSV) * gnw[c];
    scl[b][c] = sc;
    sh[b][c] = gnb[c] - m * sc;
  }
  __syncthreads();
  for (int i = t; i < 2 * 2 * 4704; i += 256) {
    int wsel = i / 9408, rem = i % 9408, b = rem / 4704, j = rem % 4704;
    int o = j / 49, c2 = j % 49;
    const float* W = wsel ? wL : wR;
    unsigned p = 0;
    if (c2 < 48) {
      float w0 = W[o * 96 + 2 * c2] * scl[b][2 * c2];
      float w1 = W[o * 96 + 2 * c2 + 1] * scl[b][2 * c2 + 1];
      p = bfr(w0) | (bfr(w1) << 16);
    }
    (wsel ? w2L : w2R)[b * 4704 + j] = p;
  }
  for (int i = t; i < 2 * 2 * 96; i += 256) {
    int wsel = i / 192, rem = i % 192, b = rem / 96, o = rem % 96;
    const float* W = wsel ? wL : wR;
    float acc = (wsel ? bL : bR)[o];
    for (int c = 0; c < 96; ++c) acc += W[o * 96 + c] * sh[b][c];
    (wsel ? b2L : b2R)[b * 96 + o] = acc;
  }
}

// collapse IN1 replicas, compute BN1(IN) affine, pack w_l2 (unscaled)
__global__ __launch_bounds__(256) void prep_l2_k(const float* __restrict__ rawIN1,
    const float* __restrict__ w, const float* __restrict__ bi,
    const float* __restrict__ bn1w, const float* __restrict__ bn1b,
    unsigned* __restrict__ w2g, float* __restrict__ b2g,
    float* __restrict__ sclg, float* __restrict__ shfg) {
  __shared__ float st[384];
  int t = threadIdx.x;
  for (int i = t; i < 384; i += 256) {
    float s = 0.f;
    for (int r = 0; r < NREP; ++r) s += rawIN1[r * 384 + i];
    st[i] = s;
  }
  __syncthreads();
  if (t < 192) {
    int b = t / 96, c = t % 96;
    const float inv = 1.f / 96000.f;
    float m0 = st[c * 2] * inv, v0 = st[c * 2 + 1] * inv - m0 * m0;
    float m1 = st[192 + c * 2] * inv, v1 = st[192 + c * 2 + 1] * inv - m1 * m1;
    float bv = 0.5f * (v0 / (v0 + EPSV) + v1 / (v1 + EPSV));
    float bscale = rsqrtf(bv + EPSV) * bn1w[c];
    float mi = b ? m1 : m0, vi = b ? v1 : v0;
    float sc = rsqrtf(vi + EPSV) * bscale;
    sclg[t] = sc;
    shfg[t] = bn1b[c] - mi * sc;
    b2g[t] = bi[c];
  }
  for (int i = t; i < 4704; i += 256) {
    int o = i / 49, c2 = i % 49;
    unsigned p = 0;
    if (c2 < 48) p = bfr(w[o * 96 + 2 * c2]) | (bfr(w[o * 96 + 2 * c2 + 1]) << 16);
    w2g[i] = p;
  }
}

// =============== conv0 via MFMA: feat & elu(feat) in HEAD-MAJOR bf16 ========
__global__ __launch_bounds__(256) void convb0_k(const float* __restrict__ xin,
    const unsigned* __restrict__ w2g,
    unsigned short* __restrict__ fb, unsigned short* __restrict__ fe) {
  __shared__ __align__(16) unsigned ldsW[96 * 49];
  __shared__ __align__(16) unsigned xt2[64 * 49];
  int tile = blockIdx.x % 1500, b = blockIdx.x / 1500;
  int nw0 = tile * 64;
  int t = threadIdx.x;
  for (int i = t; i < 1176; i += 256)
    ((float4*)ldsW)[i] = ((const float4*)w2g)[i];
  const float* xb = xin + b * CNW + nw0;
  for (int i = t; i < 768; i += 256) {
    int c2 = i >> 4, j4 = i & 15;
    const float* r0 = xb + (2 * c2) * 96000 + j4 * 4;
    float4 x0 = *(const float4*)r0;
    float4 x1 = *(const float4*)(r0 + 96000);
    int base = j4 * 4;
    xt2[(base + 0) * 49 + c2] = bfr(x0.x) | (bfr(x1.x) << 16);
    xt2[(base + 1) * 49 + c2] = bfr(x0.y) | (bfr(x1.y) << 16);
    xt2[(base + 2) * 49 + c2] = bfr(x0.z) | (bfr(x1.z) << 16);
    xt2[(base + 3) * 49 + c2] = bfr(x0.w) | (bfr(x1.w) << 16);
  }
  __syncthreads();
  int lane = t & 63, nt = t >> 6;
  int l15 = lane & 15, kg = lane >> 4;
  f32x4 acc[6];
#pragma unroll
  for (int mt = 0; mt < 6; ++mt) acc[mt] = (f32x4){0.f, 0.f, 0.f, 0.f};
#pragma unroll
  for (int ks = 0; ks < 3; ++ks) {
    int cb = ks * 16 + kg * 4;
    FragU bf;
    int brow = (nt * 16 + l15) * 49 + cb;
    bf.u[0] = xt2[brow + 0]; bf.u[1] = xt2[brow + 1];
    bf.u[2] = xt2[brow + 2]; bf.u[3] = xt2[brow + 3];
#pragma unroll
    for (int mt = 0; mt < 6; ++mt) {
      FragU af;
      int arow = (mt * 16 + l15) * 49 + cb;
      af.u[0] = ldsW[arow + 0]; af.u[1] = ldsW[arow + 1];
      af.u[2] = ldsW[arow + 2]; af.u[3] = ldsW[arow + 3];
      acc[mt] = __builtin_amdgcn_mfma_f32_16x16x32_bf16(af.v, bf.v, acc[mt], 0, 0, 0);
    }
  }
  // head-major epilogue: nwb 16-aligned => same n and same g for all 16 lanes
  int nwb = nw0 + nt * 16;
  int n = nwb / 96, w0 = nwb % 96, g = w0 >> 4;
  unsigned short* f1 = fb + (size_t)b * CNW + g * 16000 + n * 16 + l15;
  unsigned short* f2 = fe + (size_t)b * CNW + g * 16000 + n * 16 + l15;
#pragma unroll
  for (int mt = 0; mt < 6; ++mt)
#pragma unroll
    for (int r = 0; r < 4; ++r) {
      int o = mt * 16 + kg * 4 + r;
      float val = acc[mt][r];
      f1[o * 96000] = (unsigned short)bfr(val);
      f2[o * 96000] = (unsigned short)bfr(eluf(val));
    }
}

// =============== xmean: xm[b][m][cin][w] = mean_s x[b][cin][m*100+s][w] =====
__global__ __launch_bounds__(128) void xmean_k(const float* __restrict__ x,
                                               float* __restrict__ xm) {
  int cin = blockIdx.x % 96, bm = blockIdx.x / 96;   // bm = b*10+m
  int b = bm / 10, m = bm % 10;
  int t = threadIdx.x;
  if (t < 96) {
    const float* xp = x + (size_t)(b * 96 + cin) * 96000 + m * 100 * 96 + t;
    float s = 0.f;
    for (int r = 0; r < 100; ++r) s += xp[r * 96];
    xm[(bm * 96 + cin) * 96 + t] = s * 0.01f;
  }
}

// =============== qm: per (b,m) tiny GEMM W @ xm -> qmg[head][m][j] ==========
__global__ __launch_bounds__(256) void qm_k(const float* __restrict__ xm,
    const float* __restrict__ w, float* __restrict__ qmg) {
  __shared__ float Wl[96 * 97], Xl[96 * 97];
  int b = blockIdx.x / 10, m = blockIdx.x % 10;
  int t = threadIdx.x;
  for (int i = t; i < 9216; i += 256) {
    int r = i / 96, cc = i % 96;
    Wl[r * 97 + cc] = w[i];
    Xl[r * 97 + cc] = xm[((b * 10 + m) * 96 + r) * 96 + cc];
  }
  __syncthreads();
  for (int i = t; i < 9216; i += 256) {
    int c = i / 96, ww = i % 96;
    float acc = 0.f;
    for (int k = 0; k < 96; ++k) acc += Wl[c * 97 + k] * Xl[k * 97 + ww];
    int g = ww >> 4, j = ww & 15;
    qmg[(b * 576 + c * 6 + g) * 160 + m * 16 + j] = acc;
  }
}

// ---------------- collapse NREP replicas -> canonical [384] -----------------
__global__ __launch_bounds__(256) void collapse_k(const float* __restrict__ r0,
    float* __restrict__ o0, const float* __restrict__ r1, float* __restrict__ o1) {
  int t = blockIdx.x * 256 + threadIdx.x;
  const float* r = (t < 384) ? r0 : r1;
  float* o = (t < 384) ? o0 : o1;
  int i = (t < 384) ? t : t - 384;
  if (t < 768 && r) {
    float s = 0.f;
#pragma unroll
    for (int k = 0; k < NREP; ++k) s += r[k * 384 + i];
    o[i] = s;
  }
}

// =============== fused dual MFMA conv (right + l1) reading prepacked A2 =====
// A2[b][tile][c2=0..47][nw=0..63] bf16-pair u32 (written by trans_add).
// Stage tile once, B-fragments in regs reused for both weight sets.
__global__ __launch_bounds__(256) void convm2_k(const unsigned* __restrict__ a2,
    const unsigned* __restrict__ w2R, const float* __restrict__ b2R,
    const unsigned* __restrict__ w2L, const float* __restrict__ b2L,
    float* __restrict__ outR, float* __restrict__ outL,
    float* __restrict__ stR, float* __restrict__ stL) {
  __shared__ __align__(16) unsigned ldsW[2 * 96 * 49];
  __shared__ __align__(16) unsigned xt2[64 * 49];
  __shared__ float ldsB[192];
  __shared__ float ssum[4 * 96], sqsum[4 * 96];
  int tile = blockIdx.x % 1500, b = blockIdx.x / 1500;
  int nw0 = tile * 64;
  int t = threadIdx.x;
  for (int i = t; i < 1176; i += 256) {
    ((float4*)ldsW)[i] = ((const float4*)(w2R + b * 4704))[i];
    ((float4*)(ldsW + 4704))[i] = ((const float4*)(w2L + b * 4704))[i];
  }
  if (t < 192) ldsB[t] = (t < 96) ? b2R[b * 96 + t] : b2L[b * 96 + (t - 96)];
  const uint4* src = (const uint4*)(a2 + (size_t)(b * 1500 + tile) * 3072);
  for (int i = t; i < 768; i += 256) {
    uint4 v = src[i];
    int c2 = (i * 4) >> 6, nwl = (i * 4) & 63;
    xt2[(nwl + 0) * 49 + c2] = v.x;
    xt2[(nwl + 1) * 49 + c2] = v.y;
    xt2[(nwl + 2) * 49 + c2] = v.z;
    xt2[(nwl + 3) * 49 + c2] = v.w;
  }
  __syncthreads();
  int lane = t & 63, nt = t >> 6;
  int l15 = lane & 15, kg = lane >> 4;
  FragU bf[3];
#pragma unroll
  for (int ks = 0; ks < 3; ++ks) {
    int brow = (nt * 16 + l15) * 49 + ks * 16 + kg * 4;
    bf[ks].u[0] = xt2[brow + 0]; bf[ks].u[1] = xt2[brow + 1];
    bf[ks].u[2] = xt2[brow + 2]; bf[ks].u[3] = xt2[brow + 3];
  }
  f32x4 accR[6], accL[6];
#pragma unroll
  for (int mt = 0; mt < 6; ++mt) {
    accR[mt] = (f32x4){0.f, 0.f, 0.f, 0.f};
    accL[mt] = (f32x4){0.f, 0.f, 0.f, 0.f};
  }
#pragma unroll
  for (int ks = 0; ks < 3; ++ks) {
    int cb = ks * 16 + kg * 4;
#pragma unroll
    for (int mt = 0; mt < 6; ++mt) {
      FragU af;
      int arow = (mt * 16 + l15) * 49 + cb;
      af.u[0] = ldsW[arow + 0]; af.u[1] = ldsW[arow + 1];
      af.u[2] = ldsW[arow + 2]; af.u[3] = ldsW[arow + 3];
      accR[mt] = __builtin_amdgcn_mfma_f32_16x16x32_bf16(af.v, bf[ks].v, accR[mt], 0, 0, 0);
      af.u[0] = ldsW[4704 + arow + 0]; af.u[1] = ldsW[4704 + arow + 1];
      af.u[2] = ldsW[4704 + arow + 2]; af.u[3] = ldsW[4704 + arow + 3];
      accL[mt] = __builtin_amdgcn_mfma_f32_16x16x32_bf16(af.v, bf[ks].v, accL[mt], 0, 0, 0);
    }
  }
  // epilogues (R then L), reusing the stats arrays with barriers between
#pragma unroll
  for (int which = 0; which < 2; ++which) {
    f32x4* acc = which ? accL : accR;
    float* outp = which ? outL : outR;
    float* st_out = which ? stL : stR;
    int boff = which ? 96 : 0;
    float* ob = outp + b * CNW + nw0 + nt * 16 + l15;
    float sv[6][4], qv[6][4];
#pragma unroll
    for (int mt = 0; mt < 6; ++mt)
#pragma unroll
      for (int r = 0; r < 4; ++r) {
        int o = mt * 16 + kg * 4 + r;
        float val = acc[mt][r] + ldsB[boff + o];
        ob[o * 96000] = val;
        sv[mt][r] = val; qv[mt][r] = val * val;
      }
#pragma unroll
    for (int msk = 1; msk <= 8; msk <<= 1)
#pragma unroll
      for (int mt = 0; mt < 6; ++mt)
#pragma unroll
        for (int r = 0; r < 4; ++r) {
          sv[mt][r] += __shfl_xor(sv[mt][r], msk, 64);
          qv[mt][r] += __shfl_xor(qv[mt][r], msk, 64);
        }
    if (which) __syncthreads();   // previous t<96 reads done before overwrite
    if (l15 == 0)
#pragma unroll
      for (int mt = 0; mt < 6; ++mt)
#pragma unroll
        for (int r = 0; r < 4; ++r) {
          int o = mt * 16 + kg * 4 + r;
          ssum[nt * 96 + o] = sv[mt][r];
          sqsum[nt * 96 + o] = qv[mt][r];
        }
    __syncthreads();
    if (t < 96) {
      float S = ssum[t] + ssum[96 + t] + ssum[192 + t] + ssum[288 + t];
      float Q = sqsum[t] + sqsum[96 + t] + sqsum[192 + t] + sqsum[288 + t];
      float* dst = st_out + (tile & (NREP - 1)) * 384 + b * 192 + t * 2;
      atomicAdd(dst + 0, S);
      atomicAdd(dst + 1, Q);
    }
  }
}

// =============== MFMA conv (MODE 2: x' = relu(x*scl+shf)), for l2 ===========
template <int MODE, int STATS>
__global__ __launch_bounds__(256) void convm_k(const float* __restrict__ xin,
    const unsigned* __restrict__ w2g, const float* __restrict__ b2g,
    const float* __restrict__ sclg, const float* __restrict__ shfg,
    float* __restrict__ outp, float* __restrict__ st_out) {
  __shared__ __align__(16) unsigned ldsW[96 * 49];
  __shared__ __align__(16) unsigned xt2[64 * 49];
  __shared__ float ldsB[96], lS[96], lH[96];
  __shared__ float ssum[4 * 96], sqsum[4 * 96];
  int tile = blockIdx.x % 1500, b = blockIdx.x / 1500;
  int nw0 = tile * 64;
  int t = threadIdx.x;
  const unsigned* wsrc = w2g + (MODE == 1 ? b * 4704 : 0);
  for (int i = t; i < 1176; i += 256)
    ((float4*)ldsW)[i] = ((const float4*)wsrc)[i];
  if (t < 96) {
    ldsB[t] = (MODE == 0) ? 0.f : b2g[b * 96 + t];
    if (MODE == 2) { lS[t] = sclg[b * 96 + t]; lH[t] = shfg[b * 96 + t]; }
  }
  __syncthreads();
  const float* xb = xin + b * CNW + nw0;
  for (int i = t; i < 768; i += 256) {
    int c2 = i >> 4, j4 = i & 15;
    const float* r0 = xb + (2 * c2) * 96000 + j4 * 4;
    float4 x0 = *(const float4*)r0;
    float4 x1 = *(const float4*)(r0 + 96000);
    if (MODE == 2) {
      float s0 = lS[2 * c2], h0 = lH[2 * c2];
      float s1 = lS[2 * c2 + 1], h1 = lH[2 * c2 + 1];
      x0.x = fmaxf(x0.x * s0 + h0, 0.f); x0.y = fmaxf(x0.y * s0 + h0, 0.f);
      x0.z = fmaxf(x0.z * s0 + h0, 0.f); x0.w = fmaxf(x0.w * s0 + h0, 0.f);
      x1.x = fmaxf(x1.x * s1 + h1, 0.f); x1.y = fmaxf(x1.y * s1 + h1, 0.f);
      x1.z = fmaxf(x1.z * s1 + h1, 0.f); x1.w = fmaxf(x1.w * s1 + h1, 0.f);
    }
    int base = j4 * 4;
    xt2[(base + 0) * 49 + c2] = bfr(x0.x) | (bfr(x1.x) << 16);
    xt2[(base + 1) * 49 + c2] = bfr(x0.y) | (bfr(x1.y) << 16);
    xt2[(base + 2) * 49 + c2] = bfr(x0.z) | (bfr(x1.z) << 16);
    xt2[(base + 3) * 49 + c2] = bfr(x0.w) | (bfr(x1.w) << 16);
  }
  __syncthreads();
  int lane = t & 63, nt = t >> 6;
  int l15 = lane & 15, kg = lane >> 4;
  f32x4 acc[6];
#pragma unroll
  for (int mt = 0; mt < 6; ++mt) acc[mt] = (f32x4){0.f, 0.f, 0.f, 0.f};
#pragma unroll
  for (int ks = 0; ks < 3; ++ks) {
    int cb = ks * 16 + kg * 4;
    FragU bf;
    int brow = (nt * 16 + l15) * 49 + cb;
    bf.u[0] = xt2[brow + 0]; bf.u[1] = xt2[brow + 1];
    bf.u[2] = xt2[brow + 2]; bf.u[3] = xt2[brow + 3];
#pragma unroll
    for (int mt = 0; mt < 6; ++mt) {
      FragU af;
      int arow = (mt * 16 + l15) * 49 + cb;
      af.u[0] = ldsW[arow + 0]; af.u[1] = ldsW[arow + 1];
      af.u[2] = ldsW[arow + 2]; af.u[3] = ldsW[arow + 3];
      acc[mt] = __builtin_amdgcn_mfma_f32_16x16x32_bf16(af.v, bf.v, acc[mt], 0, 0, 0);
    }
  }
  float* ob = outp + b * CNW + nw0 + nt * 16 + l15;
  float sv[6][4], qv[6][4];
#pragma unroll
  for (int mt = 0; mt < 6; ++mt)
#pragma unroll
    for (int r = 0; r < 4; ++r) {
      int o = mt * 16 + kg * 4 + r;
      float val = acc[mt][r] + ldsB[o];
      ob[o * 96000] = val;
      if (STATS) { sv[mt][r] = val; qv[mt][r] = val * val; }
    }
  if (STATS) {
#pragma unroll
    for (int msk = 1; msk <= 8; msk <<= 1)
#pragma unroll
      for (int mt = 0; mt < 6; ++mt)
#pragma unroll
        for (int r = 0; r < 4; ++r) {
          sv[mt][r] += __shfl_xor(sv[mt][r], msk, 64);
          qv[mt][r] += __shfl_xor(qv[mt][r], msk, 64);
        }
    if (l15 == 0)
#pragma unroll
      for (int mt = 0; mt < 6; ++mt)
#pragma unroll
        for (int r = 0; r < 4; ++r) {
          int o = mt * 16 + kg * 4 + r;
          ssum[nt * 96 + o] = sv[mt][r];
          sqsum[nt * 96 + o] = qv[mt][r];
        }
    __syncthreads();
    if (t < 96) {
      float S = ssum[t] + ssum[96 + t] + ssum[192 + t] + ssum[288 + t];
      float Q = sqsum[t] + sqsum[96 + t] + sqsum[192 + t] + sqsum[288 + t];
      float* dst = st_out + (tile & (NREP - 1)) * 384 + b * 192 + t * 2;
      atomicAdd(dst + 0, S);
      atomicAdd(dst + 1, Q);
    }
  }
}

// ---------------- attention kernel A: sinkhorn + top3 cut (qm precomputed) --
__global__ __launch_bounds__(256) void attnA_k(const float* __restrict__ qmg,
                                               float* __restrict__ Pg) {
  int head = blockIdx.x;
  __shared__ float qm[160];
  __shared__ float L[110];
  int t = threadIdx.x;
  if (t < 160) qm[t] = qmg[head * 160 + t];
  __syncthreads();
  if (t < 100) {
    int m = t / 10, n2 = t % 10;
    float acc = 0.f;
#pragma unroll
    for (int j = 0; j < 16; ++j) acc += qm[m * 16 + j] * qm[n2 * 16 + j];
    L[m * 11 + n2] = acc * ITEMP;
  }
  __syncthreads();
  for (int it = 0; it < 8; ++it) {
    if (t < 10) {
      float mx = -3.4e38f;
      for (int n2 = 0; n2 < 10; ++n2) mx = fmaxf(mx, L[t * 11 + n2]);
      float s = 0.f;
      for (int n2 = 0; n2 < 10; ++n2) s += expf(L[t * 11 + n2] - mx);
      float lse = mx + logf(s);
      for (int n2 = 0; n2 < 10; ++n2) L[t * 11 + n2] -= lse;
    }
    __syncthreads();
    if (t < 10) {
      float mx = -3.4e38f;
      for (int m = 0; m < 10; ++m) mx = fmaxf(mx, L[m * 11 + t]);
      float s = 0.f;
      for (int m = 0; m < 10; ++m) s += expf(L[m * 11 + t] - mx);
      float lse = mx + logf(s);
      for (int m = 0; m < 10; ++m) L[m * 11 + t] -= lse;
    }
    __syncthreads();
  }
  if (t < 10) {
    float p[10];
#pragma unroll
    for (int n2 = 0; n2 < 10; ++n2) p[n2] = expf(L[t * 11 + n2]);
    int i1 = -1, i2 = -1;
    float m1 = -1.f, m2 = -1.f, m3 = -1.f;
#pragma unroll
    for (int n2 = 0; n2 < 10; ++n2) if (p[n2] > m1) { m1 = p[n2]; i1 = n2; }
#pragma unroll
    for (int n2 = 0; n2 < 10; ++n2) if (n2 != i1 && p[n2] > m2) { m2 = p[n2]; i2 = n2; }
#pragma unroll
    for (int n2 = 0; n2 < 10; ++n2) if (n2 != i1 && n2 != i2 && p[n2] > m3) m3 = p[n2];
#pragma unroll
    for (int n2 = 0; n2 < 10; ++n2)
      Pg[head * 100 + t * 10 + n2] = (p[n2] >= m3) ? p[n2] : 0.f;
  }
}

// ---------------- attention kernel B — MFMA, head-major bf16, LDS union -----
// Pitches 20/68: rows 16B-aligned so frag reads can issue as ds_read_b128
// (R13's odd 21/69 broke alignment -> 4x b32 and MORE conflicts, 9.5M).
__global__ __launch_bounds__(256) void attnB_k(
    const unsigned short* __restrict__ fbg, const unsigned short* __restrict__ feg,
    const float* __restrict__ Pg, float* __restrict__ out) {
  __shared__ __align__(16) unsigned U[7616 + 1088];
  unsigned* P2 = U;            // [112][68] (phases C,D)
  unsigned* Qs = U;            // [112][20] (phases A,B; dead before P2 write)
  unsigned* Ks = U + 2240;     // [112][20]
  unsigned* Vt = U + 7616;     // [16][68]
  int m = blockIdx.x % 10;
  int head = blockIdx.x / 10;
  int b = head / 576, rem = head % 576, c = rem / 6, grp = rem % 6;
  const unsigned* fbH = (const unsigned*)fbg + (size_t)head * 8000;
  const unsigned* feH = (const unsigned*)feg + (size_t)head * 8000;
  int t = threadIdx.x;

  // ---- phase A: stage Q, mixed K', V' (+ zero pads) ----
  for (int i = t; i < 896; i += 256) {          // d-pairs 8-15 (K 16->32 pad)
    int row = i >> 3, cc = i & 7;
    Qs[row * 20 + 8 + cc] = 0;
    Ks[row * 20 + 8 + cc] = 0;
  }
  for (int i = t; i < 96; i += 256) {           // rows 100-111, d-pairs 0-7
    int row = 100 + (i >> 3), cc = i & 7;
    Qs[row * 20 + cc] = 0;
    Ks[row * 20 + cc] = 0;
  }
  for (int i = t; i < 224; i += 256) {          // V key-pairs 50-63
    int d = i / 14, cc = i % 14;
    Vt[d * 68 + 50 + cc] = 0;
  }
  float p[10];
#pragma unroll
  for (int n2 = 0; n2 < 10; ++n2) p[n2] = Pg[head * 100 + m * 10 + n2];
  // Q: dense head-major copies (bf16 pairs ARE the k-pair format)
  for (int i = t; i < 800; i += 256) {
    int s = i >> 3, p8 = i & 7;
    Qs[s * 20 + p8] = fbH[(m * 100 + s) * 8 + p8];
  }
  // K',V' mix: thread (sp,q); dense uint2 loads from head-major buffers
  if (t < 200) {
    int sp = t >> 2, q = t & 3;
    float4 ak0 = make_float4(0.f, 0.f, 0.f, 0.f), ak1 = ak0, av0 = ak0, av1 = ak0;
#pragma unroll
    for (int n2 = 0; n2 < 10; ++n2) {
      if (p[n2] != 0.f) {
        float pe = p[n2];
        int rbase = (n2 * 100 + 2 * sp) * 8 + 2 * q;
        uint2 k01 = *(const uint2*)(fbH + rbase);
        uint2 k23 = *(const uint2*)(fbH + rbase + 8);
        uint2 e01 = *(const uint2*)(feH + rbase);
        uint2 e23 = *(const uint2*)(feH + rbase + 8);
        ak0.x += pe * blo(k01.x); ak0.y += pe * bhi(k01.x);
        ak0.z += pe * blo(k01.y); ak0.w += pe * bhi(k01.y);
        ak1.x += pe * blo(k23.x); ak1.y += pe * bhi(k23.x);
        ak1.z += pe * blo(k23.y); ak1.w += pe * bhi(k23.y);
        av0.x += pe * blo(e01.x); av0.y += pe * bhi(e01.x);
        av0.z += pe * blo(e01.y); av0.w += pe * bhi(e01.y);
        av1.x += pe * blo(e23.x); av1.y += pe * bhi(e23.x);
        av1.z += pe * blo(e23.y); av1.w += pe * bhi(e23.y);
      }
    }
    Ks[(2 * sp) * 20 + 2 * q]         = bfr(ak0.x) | (bfr(ak0.y) << 16);
    Ks[(2 * sp) * 20 + 2 * q + 1]     = bfr(ak0.z) | (bfr(ak0.w) << 16);
    Ks[(2 * sp + 1) * 20 + 2 * q]     = bfr(ak1.x) | (bfr(ak1.y) << 16);
    Ks[(2 * sp + 1) * 20 + 2 * q + 1] = bfr(ak1.z) | (bfr(ak1.w) << 16);
    Vt[(4 * q + 0) * 68 + sp] = bfr(av0.x) | (bfr(av1.x) << 16);
    Vt[(4 * q + 1) * 68 + sp] = bfr(av0.y) | (bfr(av1.y) << 16);
    Vt[(4 * q + 2) * 68 + sp] = bfr(av0.z) | (bfr(av1.z) << 16);
    Vt[(4 * q + 3) * 68 + sp] = bfr(av0.w) | (bfr(av1.w) << 16);
  }
  __syncthreads();

  // ---- phase B: QK^T into registers (S-tiles live across the barrier) ----
  int lane = t & 63, w = t >> 6;
  int l15 = lane & 15, kg = lane >> 4;
  int nmt = (w < 3) ? 2 : 1;
  f32x4 s2[2][7];
#pragma unroll
  for (int im = 0; im < 2; ++im) {
    if (im < nmt) {
      int mt = w * 2 + im;
      FragU qf;
      int qbase = (mt * 16 + l15) * 20 + kg * 4;
      qf.u[0] = Qs[qbase + 0]; qf.u[1] = Qs[qbase + 1];
      qf.u[2] = Qs[qbase + 2]; qf.u[3] = Qs[qbase + 3];
#pragma unroll
      for (int nt2 = 0; nt2 < 7; ++nt2) {
        FragU kf;
        int kbase = (nt2 * 16 + l15) * 20 + kg * 4;
        kf.u[0] = Ks[kbase + 0]; kf.u[1] = Ks[kbase + 1];
        kf.u[2] = Ks[kbase + 2]; kf.u[3] = Ks[kbase + 3];
        s2[im][nt2] = __builtin_amdgcn_mfma_f32_16x16x32_bf16(
            qf.v, kf.v, (f32x4){0.f, 0.f, 0.f, 0.f}, 0, 0, 0);
      }
    }
  }
  __syncthreads();     // all Qs/Ks reads complete; P2 may alias them now

  // ---- phase C: softmax + P2 write ----
  for (int i = t; i < 896; i += 256) {          // P2 pad key-pairs 56-63
    int row = i >> 3, cc = i & 7;
    P2[row * 68 + 56 + cc] = 0;
  }
  float rinv[2][4];
#pragma unroll
  for (int im = 0; im < 2; ++im) {
    if (im < nmt) {
      int mt = w * 2 + im;
      if (l15 >= 4) {   // mask pad key-columns 100-111 (tile 6)
        s2[im][6][0] = -3.0e38f; s2[im][6][1] = -3.0e38f;
        s2[im][6][2] = -3.0e38f; s2[im][6][3] = -3.0e38f;
      }
#pragma unroll
      for (int r = 0; r < 4; ++r) {
        float mx = s2[im][0][r];
#pragma unroll
        for (int nt2 = 1; nt2 < 7; ++nt2) mx = fmaxf(mx, s2[im][nt2][r]);
        mx = fmaxf(mx, __shfl_xor(mx, 1, 64));
        mx = fmaxf(mx, __shfl_xor(mx, 2, 64));
        mx = fmaxf(mx, __shfl_xor(mx, 4, 64));
        mx = fmaxf(mx, __shfl_xor(mx, 8, 64));
        float pv[7];
        float sum = 0.f;
#pragma unroll
        for (int nt2 = 0; nt2 < 7; ++nt2) {
          pv[nt2] = __expf((s2[im][nt2][r] - mx) * ITEMP);
          sum += pv[nt2];
        }
        sum += __shfl_xor(sum, 1, 64);
        sum += __shfl_xor(sum, 2, 64);
        sum += __shfl_xor(sum, 4, 64);
        sum += __shfl_xor(sum, 8, 64);
        rinv[im][r] = 1.f / sum;
        int row = mt * 16 + kg * 4 + r;
#pragma unroll
        for (int nt2 = 0; nt2 < 7; ++nt2) {
          float other = __shfl_xor(pv[nt2], 1, 64);
          if ((l15 & 1) == 0)
            P2[row * 68 + nt2 * 8 + (l15 >> 1)] = bfr(pv[nt2]) | (bfr(other) << 16);
        }
      }
    }
  }
  __syncthreads();

  // ---- phase D: PV ----
#pragma unroll
  for (int im = 0; im < 2; ++im) {
    if (im < nmt) {
      int mt = w * 2 + im;
      f32x4 acc = (f32x4){0.f, 0.f, 0.f, 0.f};
#pragma unroll
      for (int ks = 0; ks < 4; ++ks) {
        FragU pa, vb;
        int pbase = (mt * 16 + l15) * 68 + ks * 16 + kg * 4;
        pa.u[0] = P2[pbase + 0]; pa.u[1] = P2[pbase + 1];
        pa.u[2] = P2[pbase + 2]; pa.u[3] = P2[pbase + 3];
        int vbase = l15 * 68 + ks * 16 + kg * 4;
        vb.u[0] = Vt[vbase + 0]; vb.u[1] = Vt[vbase + 1];
        vb.u[2] = Vt[vbase + 2]; vb.u[3] = Vt[vbase + 3];
        acc = __builtin_amdgcn_mfma_f32_16x16x32_bf16(pa.v, vb.v, acc, 0, 0, 0);
      }
      float* obp = out + b * CNW + c * 96000 + grp * 16 + (m * 100) * 96 + l15;
#pragma unroll
      for (int r = 0; r < 4; ++r) {
        int row = mt * 16 + kg * 4 + r;
        if (row < 100) obp[row * 96] = acc[r] * rinv[im][r];
      }
    }
  }
}

// ------ trans_add: A2 = bf16-pairs of swapaxes(feat_attn,1,3)+x, GN stats ---
// A2[b][tile][c2][nw] is exactly convm's staged layout -> consumers skip all
// repacking AND read 37MB instead of 74. bfr() here == what convm staged.
__global__ __launch_bounds__(256) void trans_add_k(const float* __restrict__ z,
    const float* __restrict__ x, unsigned* __restrict__ a2,
    float* __restrict__ rawGN) {
  __shared__ float ld[96 * 97];
  __shared__ float red[4 * 12];
  int b = blockIdx.x / 1000, n = blockIdx.x % 1000;
  int t = threadIdx.x;
  const float* zp = z + b * CNW + n * 96;
  for (int i = t; i < 9216; i += 256) {
    int r = i / 96, col = i % 96;
    ld[r * 97 + col] = zp[r * 96000 + col];
  }
  __syncthreads();
  const float* xp = x + b * CNW + n * 96;
  unsigned* ab = a2 + (size_t)b * 1500 * 3072;
  float sg[6], qg[6];
#pragma unroll
  for (int g = 0; g < 6; ++g) { sg[g] = 0.f; qg[g] = 0.f; }
#pragma unroll
  for (int k = 0; k < 18; ++k) {
    int i = t + k * 256;
    int g = k / 3;                    // = i/768, compile-time under unroll
    int cc2 = i / 96, ww = i % 96;
    int c0 = 2 * cc2;
    float v0 = ld[ww * 97 + c0] + xp[c0 * 96000 + ww];
    float v1 = ld[ww * 97 + c0 + 1] + xp[(c0 + 1) * 96000 + ww];
    int nw = n * 96 + ww;
    ab[(size_t)(nw >> 6) * 3072 + cc2 * 64 + (nw & 63)] = bfr(v0) | (bfr(v1) << 16);
    sg[g] += v0 + v1;
    qg[g] += v0 * v0 + v1 * v1;
  }
#pragma unroll
  for (int msk = 1; msk <= 32; msk <<= 1)
#pragma unroll
    for (int g = 0; g < 6; ++g) {
      sg[g] += __shfl_xor(sg[g], msk, 64);
      qg[g] += __shfl_xor(qg[g], msk, 64);
    }
  int wid = t >> 6;
  if ((t & 63) == 0)
#pragma unroll
    for (int g = 0; g < 6; ++g) {
      red[wid * 12 + g * 2 + 0] = sg[g];
      red[wid * 12 + g * 2 + 1] = qg[g];
    }
  __syncthreads();
  if (t < 12) {
    float s = red[t] + red[12 + t] + red[24 + t] + red[36 + t];
    atomicAdd(&rawGN[(n & (NREP - 1)) * 24 + b * 12 + t], s);
  }
}

// ---------------- out = relu( BN2(IN(l2)) + BNr(right_raw) ) -----------------
__global__ __launch_bounds__(256) void final_k(float* __restrict__ outp,
    const float* __restrict__ l2, const float* __restrict__ stR,
    const float* __restrict__ st2, const float* __restrict__ rw,
    const float* __restrict__ rb, const float* __restrict__ w2,
    const float* __restrict__ b2) {
  int stride = gridDim.x * 256;
  for (int i4 = blockIdx.x * 256 + threadIdx.x; i4 < 4608000; i4 += stride) {
    int i = i4 * 4;
    int b = i / CNW, o = (i / 96000) % 96;
    float mr = (stR[o * 2] + stR[192 + o * 2]) * (1.f / 192000.f);
    float vr = (stR[o * 2 + 1] + stR[192 + o * 2 + 1]) * (1.f / 192000.f) - mr * mr;
    float rs = rsqrtf(vr + EPSV) * rw[o];
    float rsh = rb[o] - mr * rs;
    const float inv = 1.f / 96000.f;
    float m0 = st2[o * 2] * inv,       v0 = st2[o * 2 + 1] * inv - m0 * m0;
    float m1 = st2[192 + o * 2] * inv, v1 = st2[192 + o * 2 + 1] * inv - m1 * m1;
    float bv = 0.5f * (v0 / (v0 + EPSV) + v1 / (v1 + EPSV));
    float ls = rsqrtf(bv + EPSV) * w2[o];
    float mi = b ? m1 : m0, vi = b ? v1 : v0;
    float lsc = rsqrtf(vi + EPSV) * ls;
    float lsh = b2[o] - mi * lsc;
    float4 R = ((float4*)outp)[i4];
    float4 L = ((const float4*)l2)[i4];
    float4 O;
    O.x = fmaxf(R.x * rs + rsh + L.x * lsc + lsh, 0.f);
    O.y = fmaxf(R.y * rs + rsh + L.y * lsc + lsh, 0.f);
    O.z = fmaxf(R.z * rs + rsh + L.z * lsc + lsh, 0.f);
    O.w = fmaxf(R.w * rs + rsh + L.w * lsc + lsh, 0.f);
    ((float4*)outp)[i4] = O;
  }
}

extern "C" void kernel_launch(void* const* d_in, const int* in_sizes, int n_in,
                              void* d_out, int out_size, void* d_ws, size_t ws_size,
                              hipStream_t stream) {
  const float* x        = (const float*)d_in[0];
  const float* w_linear = (const float*)d_in[1];
  const float* gn_w     = (const float*)d_in[2];
  const float* gn_b     = (const float*)d_in[3];
  const float* w_right  = (const float*)d_in[4];
  const float* b_right  = (const float*)d_in[5];
  const float* bn_r_w   = (const float*)d_in[6];
  const float* bn_r_b   = (const float*)d_in[7];
  const float* w_l1     = (const float*)d_in[8];
  const float* b_l1     = (const float*)d_in[9];
  const float* bn1_w    = (const float*)d_in[10];
  const float* bn1_b    = (const float*)d_in[11];
  const float* w_l2     = (const float*)d_in[12];
  const float* b_l2     = (const float*)d_in[13];
  const float* bn2_w    = (const float*)d_in[14];
  const float* bn2_b    = (const float*)d_in[15];
  float* out = (float*)d_out;

  float* A      = (float*)d_ws;            // TOT floats
  unsigned short* featb = (unsigned short*)A;     // TOT ushorts (head-major)
  unsigned short* felub = featb + TOT;            // TOT ushorts (head-major)
  unsigned* a2  = (unsigned*)featb;        // TOT/2 u32 (reuses featb after attnB)
  float* Bb     = A + TOT;                 // TOT floats (attn out, later l1)
  float* Pg     = Bb + TOT;                // 115200
  float* rawGN  = Pg + 115200;             // NREP*24 = 384
  float* rawBNr = rawGN + NREP * 24;       // NREP*384
  float* rawIN1 = rawBNr + NREP * 384;     // NREP*384
  float* rawIN2 = rawIN1 + NREP * 384;     // NREP*384
  float* stBNr  = rawIN2 + NREP * 384;     // 384
  float* stIN2  = stBNr + 384;             // 384
  unsigned* w2_0  = (unsigned*)(stIN2 + 384);  // 4704
  unsigned* w2R   = w2_0 + 4704;               // 2*4704
  unsigned* w2L   = w2R + 2 * 4704;            // 2*4704
  unsigned* w2l2  = w2L + 2 * 4704;            // 4704
  float* b2R   = (float*)(w2l2 + 4704);        // 192
  float* b2L   = b2R + 192;                    // 192
  float* b2l2  = b2L + 192;                    // 192
  float* scl1g = b2l2 + 192;                   // 192
  float* shf1g = scl1g + 192;                  // 192
  float* xm    = shf1g + 192;                  // 184320
  float* qmg   = xm + 184320;                  // 184320

  hipMemsetAsync(rawGN, 0, (NREP * 24 + 3 * NREP * 384) * sizeof(float), stream);

  prep0_k<<<1, 256, 0, stream>>>(w_linear, w2_0);
  // feat (+elu) = conv1x1(x, w_linear) -> featb/felub (head-major bf16, MFMA)
  convb0_k<<<3000, 256, 0, stream>>>(x, w2_0, featb, felub);
  // exact fp32 path for the sinkhorn cut: xm = mean_s(x), qm = W @ xm
  xmean_k<<<1920, 128, 0, stream>>>(x, xm);
  qm_k<<<20, 256, 0, stream>>>(xm, w_linear, qmg);
  attnA_k<<<1152, 256, 0, stream>>>(qmg, Pg);
  // attention -> Bb
  attnB_k<<<11520, 256, 0, stream>>>(featb, felub, Pg, Bb);
  // A2 = bf16-pair(t + x) in convm layout (featb dead); fused GN stats
  trans_add_k<<<2000, 256, 0, stream>>>(Bb, x, a2, rawGN);
  prep_rl_k<<<1, 256, 0, stream>>>(rawGN, w_right, b_right, w_l1, b_l1,
                                   gn_w, gn_b, w2R, b2R, w2L, b2L);
  // fused right + l1 convs from A2 (Bb free after trans_add read it)
  convm2_k<<<3000, 256, 0, stream>>>(a2, w2R, b2R, w2L, b2L,
                                     out, Bb, rawBNr, rawIN1);
  prep_l2_k<<<1, 256, 0, stream>>>(rawIN1, w_l2, b_l2, bn1_w, bn1_b,
                                   w2l2, b2l2, scl1g, shf1g);
  // l2 = conv(relu(BN1(IN(l1)))) -> A fp32 (a2 dead, safe to clobber)
  convm_k<2, 1><<<3000, 256, 0, stream>>>(Bb, w2l2, b2l2, scl1g, shf1g,
                                          A, rawIN2);
  collapse_k<<<3, 256, 0, stream>>>(rawBNr, stBNr, rawIN2, stIN2);
  final_k<<<2048, 256, 0, stream>>>(out, A, stBNr, stIN2,
                                    bn_r_w, bn_r_b, bn2_w, bn2_b);
}

// Round 15
// 515.420 us; speedup vs baseline: 1.1266x; 1.0620x over previous
//
#include <hip/hip_runtime.h>
#include <math.h>

#define CNW 9216000      // C*N*W = 96*1000*96
#define TOT 18432000     // B*C*N*W
#define EPSV 1e-5f
#define ITEMP 0.10206207261596575f   // 1/sqrt(96)
#define NREP 16          // stats replicas (breaks same-address atomic chains)

typedef __attribute__((ext_vector_type(8))) short bf16x8;   // 8 bf16 = 4 VGPR
typedef __attribute__((ext_vector_type(4))) float f32x4;

union FragU { unsigned u[4]; bf16x8 v; };

// round-to-nearest-even fp32 -> bf16 (upper 16 bits)
__device__ __forceinline__ unsigned bfr(float x) {
  union { float f; unsigned u; } v; v.f = x;
  return (v.u + 0x7fffu + ((v.u >> 16) & 1u)) >> 16;
}
__device__ __forceinline__ float eluf(float x) {
  return fmaxf(x, 0.f) + __expf(fminf(x, 0.f)) - 1.f;
}
// unpack bf16 pair (u32) -> fp32 (exact)
__device__ __forceinline__ float blo(unsigned u) {
  union { unsigned x; float f; } v; v.x = u << 16; return v.f;
}
__device__ __forceinline__ float bhi(unsigned u) {
  union { unsigned x; float f; } v; v.x = u & 0xffff0000u; return v.f;
}

// =============== prep: pack weights into bf16 k-pair layout =================
__global__ __launch_bounds__(256) void prep0_k(const float* __restrict__ w,
                                               unsigned* __restrict__ w2g) {
  int t = threadIdx.x;
  for (int i = t; i < 4704; i += 256) {
    int o = i / 49, c2 = i % 49;
    unsigned p = 0;
    if (c2 < 48) p = bfr(w[o * 96 + 2 * c2]) | (bfr(w[o * 96 + 2 * c2 + 1]) << 16);
    w2g[i] = p;
  }
}

// collapse GN replicas, fold GN scale into w_right/w_l1 (per b), exact bias2
__global__ __launch_bounds__(256) void prep_rl_k(const float* __restrict__ rawGN,
    const float* __restrict__ wR, const float* __restrict__ bR,
    const float* __restrict__ wL, const float* __restrict__ bL,
    const float* __restrict__ gnw, const float* __restrict__ gnb,
    unsigned* __restrict__ w2R, float* __restrict__ b2R,
    unsigned* __restrict__ w2L, float* __restrict__ b2L) {
  __shared__ float stGN[24];
  __shared__ float scl[2][96], sh[2][96];
  int t = threadIdx.x;
  if (t < 24) {
    float s = 0.f;
    for (int r = 0; r < NREP; ++r) s += rawGN[r * 24 + t];
    stGN[t] = s;
  }
  __syncthreads();
  if (t < 192) {
    int b = t / 96, c = t % 96, g = c >> 4;
    float m = stGN[b * 12 + g * 2] * (1.f / 1536000.f);
    float v = stGN[b * 12 + g * 2 + 1] * (1.f / 1536000.f) - m * m;
    float sc = rsqrtf(v + EPSV) * gnw[c];
    scl[b][c] = sc;
    sh[b][c] = gnb[c] - m * sc;
  }
  __syncthreads();
  for (int i = t; i < 2 * 2 * 4704; i += 256) {
    int wsel = i / 9408, rem = i % 9408, b = rem / 4704, j = rem % 4704;
    int o = j / 49, c2 = j % 49;
    const float* W = wsel ? wL : wR;
    unsigned p = 0;
    if (c2 < 48) {
      float w0 = W[o * 96 + 2 * c2] * scl[b][2 * c2];
      float w1 = W[o * 96 + 2 * c2 + 1] * scl[b][2 * c2 + 1];
      p = bfr(w0) | (bfr(w1) << 16);
    }
    (wsel ? w2L : w2R)[b * 4704 + j] = p;
  }
  for (int i = t; i < 2 * 2 * 96; i += 256) {
    int wsel = i / 192, rem = i % 192, b = rem / 96, o = rem % 96;
    const float* W = wsel ? wL : wR;
    float acc = (wsel ? bL : bR)[o];
    for (int c = 0; c < 96; ++c) acc += W[o * 96 + c] * sh[b][c];
    (wsel ? b2L : b2R)[b * 96 + o] = acc;
  }
}

// collapse IN1 replicas, compute BN1(IN) affine, pack w_l2 (unscaled)
__global__ __launch_bounds__(256) void prep_l2_k(const float* __restrict__ rawIN1,
    const float* __restrict__ w, const float* __restrict__ bi,
    const float* __restrict__ bn1w, const float* __restrict__ bn1b,
    unsigned* __restrict__ w2g, float* __restrict__ b2g,
    float* __restrict__ sclg, float* __restrict__ shfg) {
  __shared__ float st[384];
  int t = threadIdx.x;
  for (int i = t; i < 384; i += 256) {
    float s = 0.f;
    for (int r = 0; r < NREP; ++r) s += rawIN1[r * 384 + i];
    st[i] = s;
  }
  __syncthreads();
  if (t < 192) {
    int b = t / 96, c = t % 96;
    const float inv = 1.f / 96000.f;
    float m0 = st[c * 2] * inv, v0 = st[c * 2 + 1] * inv - m0 * m0;
    float m1 = st[192 + c * 2] * inv, v1 = st[192 + c * 2 + 1] * inv - m1 * m1;
    float bv = 0.5f * (v0 / (v0 + EPSV) + v1 / (v1 + EPSV));
    float bscale = rsqrtf(bv + EPSV) * bn1w[c];
    float mi = b ? m1 : m0, vi = b ? v1 : v0;
    float sc = rsqrtf(vi + EPSV) * bscale;
    sclg[t] = sc;
    shfg[t] = bn1b[c] - mi * sc;
    b2g[t] = bi[c];
  }
  for (int i = t; i < 4704; i += 256) {
    int o = i / 49, c2 = i % 49;
    unsigned p = 0;
    if (c2 < 48) p = bfr(w[o * 96 + 2 * c2]) | (bfr(w[o * 96 + 2 * c2 + 1]) << 16);
    w2g[i] = p;
  }
}

// =============== conv0 via MFMA: feat & elu(feat) in HEAD-MAJOR bf16 ========
__global__ __launch_bounds__(256) void convb0_k(const float* __restrict__ xin,
    const unsigned* __restrict__ w2g,
    unsigned short* __restrict__ fb, unsigned short* __restrict__ fe) {
  __shared__ __align__(16) unsigned ldsW[96 * 49];
  __shared__ __align__(16) unsigned xt2[64 * 49];
  int tile = blockIdx.x % 1500, b = blockIdx.x / 1500;
  int nw0 = tile * 64;
  int t = threadIdx.x;
  for (int i = t; i < 1176; i += 256)
    ((float4*)ldsW)[i] = ((const float4*)w2g)[i];
  const float* xb = xin + b * CNW + nw0;
  for (int i = t; i < 768; i += 256) {
    int c2 = i >> 4, j4 = i & 15;
    const float* r0 = xb + (2 * c2) * 96000 + j4 * 4;
    float4 x0 = *(const float4*)r0;
    float4 x1 = *(const float4*)(r0 + 96000);
    int base = j4 * 4;
    xt2[(base + 0) * 49 + c2] = bfr(x0.x) | (bfr(x1.x) << 16);
    xt2[(base + 1) * 49 + c2] = bfr(x0.y) | (bfr(x1.y) << 16);
    xt2[(base + 2) * 49 + c2] = bfr(x0.z) | (bfr(x1.z) << 16);
    xt2[(base + 3) * 49 + c2] = bfr(x0.w) | (bfr(x1.w) << 16);
  }
  __syncthreads();
  int lane = t & 63, nt = t >> 6;
  int l15 = lane & 15, kg = lane >> 4;
  f32x4 acc[6];
#pragma unroll
  for (int mt = 0; mt < 6; ++mt) acc[mt] = (f32x4){0.f, 0.f, 0.f, 0.f};
#pragma unroll
  for (int ks = 0; ks < 3; ++ks) {
    int cb = ks * 16 + kg * 4;
    FragU bf;
    int brow = (nt * 16 + l15) * 49 + cb;
    bf.u[0] = xt2[brow + 0]; bf.u[1] = xt2[brow + 1];
    bf.u[2] = xt2[brow + 2]; bf.u[3] = xt2[brow + 3];
#pragma unroll
    for (int mt = 0; mt < 6; ++mt) {
      FragU af;
      int arow = (mt * 16 + l15) * 49 + cb;
      af.u[0] = ldsW[arow + 0]; af.u[1] = ldsW[arow + 1];
      af.u[2] = ldsW[arow + 2]; af.u[3] = ldsW[arow + 3];
      acc[mt] = __builtin_amdgcn_mfma_f32_16x16x32_bf16(af.v, bf.v, acc[mt], 0, 0, 0);
    }
  }
  // head-major epilogue: nwb 16-aligned => same n and same g for all 16 lanes
  int nwb = nw0 + nt * 16;
  int n = nwb / 96, w0 = nwb % 96, g = w0 >> 4;
  unsigned short* f1 = fb + (size_t)b * CNW + g * 16000 + n * 16 + l15;
  unsigned short* f2 = fe + (size_t)b * CNW + g * 16000 + n * 16 + l15;
#pragma unroll
  for (int mt = 0; mt < 6; ++mt)
#pragma unroll
    for (int r = 0; r < 4; ++r) {
      int o = mt * 16 + kg * 4 + r;
      float val = acc[mt][r];
      f1[o * 96000] = (unsigned short)bfr(val);
      f2[o * 96000] = (unsigned short)bfr(eluf(val));
    }
}

// =============== xmean: xm[b][m][cin][w] = mean_s x[b][cin][m*100+s][w] =====
__global__ __launch_bounds__(128) void xmean_k(const float* __restrict__ x,
                                               float* __restrict__ xm) {
  int cin = blockIdx.x % 96, bm = blockIdx.x / 96;   // bm = b*10+m
  int b = bm / 10, m = bm % 10;
  int t = threadIdx.x;
  if (t < 96) {
    const float* xp = x + (size_t)(b * 96 + cin) * 96000 + m * 100 * 96 + t;
    float s = 0.f;
    for (int r = 0; r < 100; ++r) s += xp[r * 96];
    xm[(bm * 96 + cin) * 96 + t] = s * 0.01f;
  }
}

// =============== qm: per (b,m) tiny GEMM W @ xm -> qmg[head][m][j] ==========
__global__ __launch_bounds__(256) void qm_k(const float* __restrict__ xm,
    const float* __restrict__ w, float* __restrict__ qmg) {
  __shared__ float Wl[96 * 97], Xl[96 * 97];
  int b = blockIdx.x / 10, m = blockIdx.x % 10;
  int t = threadIdx.x;
  for (int i = t; i < 9216; i += 256) {
    int r = i / 96, cc = i % 96;
    Wl[r * 97 + cc] = w[i];
    Xl[r * 97 + cc] = xm[((b * 10 + m) * 96 + r) * 96 + cc];
  }
  __syncthreads();
  for (int i = t; i < 9216; i += 256) {
    int c = i / 96, ww = i % 96;
    float acc = 0.f;
    for (int k = 0; k < 96; ++k) acc += Wl[c * 97 + k] * Xl[k * 97 + ww];
    int g = ww >> 4, j = ww & 15;
    qmg[(b * 576 + c * 6 + g) * 160 + m * 16 + j] = acc;
  }
}

// ---------------- collapse NREP replicas -> canonical [384] -----------------
__global__ __launch_bounds__(256) void collapse_k(const float* __restrict__ r0,
    float* __restrict__ o0, const float* __restrict__ r1, float* __restrict__ o1) {
  int t = blockIdx.x * 256 + threadIdx.x;
  const float* r = (t < 384) ? r0 : r1;
  float* o = (t < 384) ? o0 : o1;
  int i = (t < 384) ? t : t - 384;
  if (t < 768 && r) {
    float s = 0.f;
#pragma unroll
    for (int k = 0; k < NREP; ++k) s += r[k * 384 + i];
    o[i] = s;
  }
}

// =============== fused dual MFMA conv (right + l1) reading prepacked A2 =====
// right -> bf16 plain [b][o][nw] (only consumed by final's smooth BN affine).
// l1 -> packed k-pair layout a2L (only consumed as the l2 conv's MFMA input).
__global__ __launch_bounds__(256) void convm2_k(const unsigned* __restrict__ a2,
    const unsigned* __restrict__ w2R, const float* __restrict__ b2R,
    const unsigned* __restrict__ w2L, const float* __restrict__ b2L,
    unsigned short* __restrict__ outR, unsigned* __restrict__ a2L,
    float* __restrict__ stR, float* __restrict__ stL) {
  __shared__ __align__(16) unsigned ldsW[2 * 96 * 49];
  __shared__ __align__(16) unsigned xt2[64 * 49];
  __shared__ float ldsB[192];
  __shared__ float ssum[4 * 96], sqsum[4 * 96];
  int tile = blockIdx.x % 1500, b = blockIdx.x / 1500;
  int nw0 = tile * 64;
  int t = threadIdx.x;
  for (int i = t; i < 1176; i += 256) {
    ((float4*)ldsW)[i] = ((const float4*)(w2R + b * 4704))[i];
    ((float4*)(ldsW + 4704))[i] = ((const float4*)(w2L + b * 4704))[i];
  }
  if (t < 192) ldsB[t] = (t < 96) ? b2R[b * 96 + t] : b2L[b * 96 + (t - 96)];
  const uint4* src = (const uint4*)(a2 + (size_t)(b * 1500 + tile) * 3072);
  for (int i = t; i < 768; i += 256) {
    uint4 v = src[i];
    int c2 = (i * 4) >> 6, nwl = (i * 4) & 63;
    xt2[(nwl + 0) * 49 + c2] = v.x;
    xt2[(nwl + 1) * 49 + c2] = v.y;
    xt2[(nwl + 2) * 49 + c2] = v.z;
    xt2[(nwl + 3) * 49 + c2] = v.w;
  }
  __syncthreads();
  int lane = t & 63, nt = t >> 6;
  int l15 = lane & 15, kg = lane >> 4;
  FragU bf[3];
#pragma unroll
  for (int ks = 0; ks < 3; ++ks) {
    int brow = (nt * 16 + l15) * 49 + ks * 16 + kg * 4;
    bf[ks].u[0] = xt2[brow + 0]; bf[ks].u[1] = xt2[brow + 1];
    bf[ks].u[2] = xt2[brow + 2]; bf[ks].u[3] = xt2[brow + 3];
  }
  f32x4 accR[6], accL[6];
#pragma unroll
  for (int mt = 0; mt < 6; ++mt) {
    accR[mt] = (f32x4){0.f, 0.f, 0.f, 0.f};
    accL[mt] = (f32x4){0.f, 0.f, 0.f, 0.f};
  }
#pragma unroll
  for (int ks = 0; ks < 3; ++ks) {
    int cb = ks * 16 + kg * 4;
#pragma unroll
    for (int mt = 0; mt < 6; ++mt) {
      FragU af;
      int arow = (mt * 16 + l15) * 49 + cb;
      af.u[0] = ldsW[arow + 0]; af.u[1] = ldsW[arow + 1];
      af.u[2] = ldsW[arow + 2]; af.u[3] = ldsW[arow + 3];
      accR[mt] = __builtin_amdgcn_mfma_f32_16x16x32_bf16(af.v, bf[ks].v, accR[mt], 0, 0, 0);
      af.u[0] = ldsW[4704 + arow + 0]; af.u[1] = ldsW[4704 + arow + 1];
      af.u[2] = ldsW[4704 + arow + 2]; af.u[3] = ldsW[4704 + arow + 3];
      accL[mt] = __builtin_amdgcn_mfma_f32_16x16x32_bf16(af.v, bf[ks].v, accL[mt], 0, 0, 0);
    }
  }
  // epilogues: stats from fp32 vals (pre-rounding), data stored bf16
#pragma unroll
  for (int which = 0; which < 2; ++which) {
    f32x4* acc = which ? accL : accR;
    float* st_out = which ? stL : stR;
    int boff = which ? 96 : 0;
    float sv[6][4], qv[6][4];
    if (which == 0) {
      unsigned short* obR = outR + (size_t)b * CNW + nw0 + nt * 16 + l15;
#pragma unroll
      for (int mt = 0; mt < 6; ++mt)
#pragma unroll
        for (int r = 0; r < 4; ++r) {
          int o = mt * 16 + kg * 4 + r;
          float val = acc[mt][r] + ldsB[boff + o];
          obR[o * 96000] = (unsigned short)bfr(val);
          sv[mt][r] = val; qv[mt][r] = val * val;
        }
    } else {
      unsigned* obL = a2L + (size_t)(b * 1500 + tile) * 3072 + nt * 16 + l15;
#pragma unroll
      for (int mt = 0; mt < 6; ++mt)
#pragma unroll
        for (int rp = 0; rp < 4; rp += 2) {
          int o = mt * 16 + kg * 4 + rp;
          float v0 = acc[mt][rp] + ldsB[boff + o];
          float v1 = acc[mt][rp + 1] + ldsB[boff + o + 1];
          obL[(mt * 8 + kg * 2 + (rp >> 1)) * 64] = bfr(v0) | (bfr(v1) << 16);
          sv[mt][rp] = v0; qv[mt][rp] = v0 * v0;
          sv[mt][rp + 1] = v1; qv[mt][rp + 1] = v1 * v1;
        }
    }
#pragma unroll
    for (int msk = 1; msk <= 8; msk <<= 1)
#pragma unroll
      for (int mt = 0; mt < 6; ++mt)
#pragma unroll
        for (int r = 0; r < 4; ++r) {
          sv[mt][r] += __shfl_xor(sv[mt][r], msk, 64);
          qv[mt][r] += __shfl_xor(qv[mt][r], msk, 64);
        }
    if (which) __syncthreads();   // previous t<96 reads done before overwrite
    if (l15 == 0)
#pragma unroll
      for (int mt = 0; mt < 6; ++mt)
#pragma unroll
        for (int r = 0; r < 4; ++r) {
          int o = mt * 16 + kg * 4 + r;
          ssum[nt * 96 + o] = sv[mt][r];
          sqsum[nt * 96 + o] = qv[mt][r];
        }
    __syncthreads();
    if (t < 96) {
      float S = ssum[t] + ssum[96 + t] + ssum[192 + t] + ssum[288 + t];
      float Q = sqsum[t] + sqsum[96 + t] + sqsum[192 + t] + sqsum[288 + t];
      float* dst = st_out + (tile & (NREP - 1)) * 384 + b * 192 + t * 2;
      atomicAdd(dst + 0, S);
      atomicAdd(dst + 1, Q);
    }
  }
}

// =============== l2 conv: packed a2L in, relu(x*scl+shf) transform, bf16 out
__global__ __launch_bounds__(256) void convmP_k(const unsigned* __restrict__ a2L,
    const unsigned* __restrict__ w2g, const float* __restrict__ b2g,
    const float* __restrict__ sclg, const float* __restrict__ shfg,
    unsigned short* __restrict__ outb, float* __restrict__ st_out) {
  __shared__ __align__(16) unsigned ldsW[96 * 49];
  __shared__ __align__(16) unsigned xt2[64 * 49];
  __shared__ float ldsB[96], lS[96], lH[96];
  __shared__ float ssum[4 * 96], sqsum[4 * 96];
  int tile = blockIdx.x % 1500, b = blockIdx.x / 1500;
  int nw0 = tile * 64;
  int t = threadIdx.x;
  for (int i = t; i < 1176; i += 256)
    ((float4*)ldsW)[i] = ((const float4*)w2g)[i];
  if (t < 96) {
    ldsB[t] = b2g[b * 96 + t];
    lS[t] = sclg[b * 96 + t];
    lH[t] = shfg[b * 96 + t];
  }
  __syncthreads();
  const uint4* src = (const uint4*)(a2L + (size_t)(b * 1500 + tile) * 3072);
  for (int i = t; i < 768; i += 256) {
    uint4 v = src[i];
    int c2 = (i * 4) >> 6, nwl = (i * 4) & 63;
    float s0 = lS[2 * c2], h0 = lH[2 * c2];
    float s1 = lS[2 * c2 + 1], h1 = lH[2 * c2 + 1];
    unsigned uu[4] = {v.x, v.y, v.z, v.w};
#pragma unroll
    for (int j = 0; j < 4; ++j) {
      float lo = fmaxf(blo(uu[j]) * s0 + h0, 0.f);
      float hi = fmaxf(bhi(uu[j]) * s1 + h1, 0.f);
      xt2[(nwl + j) * 49 + c2] = bfr(lo) | (bfr(hi) << 16);
    }
  }
  __syncthreads();
  int lane = t & 63, nt = t >> 6;
  int l15 = lane & 15, kg = lane >> 4;
  f32x4 acc[6];
#pragma unroll
  for (int mt = 0; mt < 6; ++mt) acc[mt] = (f32x4){0.f, 0.f, 0.f, 0.f};
#pragma unroll
  for (int ks = 0; ks < 3; ++ks) {
    int cb = ks * 16 + kg * 4;
    FragU bf;
    int brow = (nt * 16 + l15) * 49 + cb;
    bf.u[0] = xt2[brow + 0]; bf.u[1] = xt2[brow + 1];
    bf.u[2] = xt2[brow + 2]; bf.u[3] = xt2[brow + 3];
#pragma unroll
    for (int mt = 0; mt < 6; ++mt) {
      FragU af;
      int arow = (mt * 16 + l15) * 49 + cb;
      af.u[0] = ldsW[arow + 0]; af.u[1] = ldsW[arow + 1];
      af.u[2] = ldsW[arow + 2]; af.u[3] = ldsW[arow + 3];
      acc[mt] = __builtin_amdgcn_mfma_f32_16x16x32_bf16(af.v, bf.v, acc[mt], 0, 0, 0);
    }
  }
  unsigned short* ob = outb + (size_t)b * CNW + nw0 + nt * 16 + l15;
  float sv[6][4], qv[6][4];
#pragma unroll
  for (int mt = 0; mt < 6; ++mt)
#pragma unroll
    for (int r = 0; r < 4; ++r) {
      int o = mt * 16 + kg * 4 + r;
      float val = acc[mt][r] + ldsB[o];
      ob[o * 96000] = (unsigned short)bfr(val);
      sv[mt][r] = val; qv[mt][r] = val * val;
    }
#pragma unroll
  for (int msk = 1; msk <= 8; msk <<= 1)
#pragma unroll
    for (int mt = 0; mt < 6; ++mt)
#pragma unroll
      for (int r = 0; r < 4; ++r) {
        sv[mt][r] += __shfl_xor(sv[mt][r], msk, 64);
        qv[mt][r] += __shfl_xor(qv[mt][r], msk, 64);
      }
  if (l15 == 0)
#pragma unroll
    for (int mt = 0; mt < 6; ++mt)
#pragma unroll
      for (int r = 0; r < 4; ++r) {
        int o = mt * 16 + kg * 4 + r;
        ssum[nt * 96 + o] = sv[mt][r];
        sqsum[nt * 96 + o] = qv[mt][r];
      }
  __syncthreads();
  if (t < 96) {
    float S = ssum[t] + ssum[96 + t] + ssum[192 + t] + ssum[288 + t];
    float Q = sqsum[t] + sqsum[96 + t] + sqsum[192 + t] + sqsum[288 + t];
    float* dst = st_out + (tile & (NREP - 1)) * 384 + b * 192 + t * 2;
    atomicAdd(dst + 0, S);
    atomicAdd(dst + 1, Q);
  }
}

// ---------------- attention kernel A: sinkhorn + top3 cut (qm precomputed) --
__global__ __launch_bounds__(256) void attnA_k(const float* __restrict__ qmg,
                                               float* __restrict__ Pg) {
  int head = blockIdx.x;
  __shared__ float qm[160];
  __shared__ float L[110];
  int t = threadIdx.x;
  if (t < 160) qm[t] = qmg[head * 160 + t];
  __syncthreads();
  if (t < 100) {
    int m = t / 10, n2 = t % 10;
    float acc = 0.f;
#pragma unroll
    for (int j = 0; j < 16; ++j) acc += qm[m * 16 + j] * qm[n2 * 16 + j];
    L[m * 11 + n2] = acc * ITEMP;
  }
  __syncthreads();
  for (int it = 0; it < 8; ++it) {
    if (t < 10) {
      float mx = -3.4e38f;
      for (int n2 = 0; n2 < 10; ++n2) mx = fmaxf(mx, L[t * 11 + n2]);
      float s = 0.f;
      for (int n2 = 0; n2 < 10; ++n2) s += expf(L[t * 11 + n2] - mx);
      float lse = mx + logf(s);
      for (int n2 = 0; n2 < 10; ++n2) L[t * 11 + n2] -= lse;
    }
    __syncthreads();
    if (t < 10) {
      float mx = -3.4e38f;
      for (int m = 0; m < 10; ++m) mx = fmaxf(mx, L[m * 11 + t]);
      float s = 0.f;
      for (int m = 0; m < 10; ++m) s += expf(L[m * 11 + t] - mx);
      float lse = mx + logf(s);
      for (int m = 0; m < 10; ++m) L[m * 11 + t] -= lse;
    }
    __syncthreads();
  }
  if (t < 10) {
    float p[10];
#pragma unroll
    for (int n2 = 0; n2 < 10; ++n2) p[n2] = expf(L[t * 11 + n2]);
    int i1 = -1, i2 = -1;
    float m1 = -1.f, m2 = -1.f, m3 = -1.f;
#pragma unroll
    for (int n2 = 0; n2 < 10; ++n2) if (p[n2] > m1) { m1 = p[n2]; i1 = n2; }
#pragma unroll
    for (int n2 = 0; n2 < 10; ++n2) if (n2 != i1 && p[n2] > m2) { m2 = p[n2]; i2 = n2; }
#pragma unroll
    for (int n2 = 0; n2 < 10; ++n2) if (n2 != i1 && n2 != i2 && p[n2] > m3) m3 = p[n2];
#pragma unroll
    for (int n2 = 0; n2 < 10; ++n2)
      Pg[head * 100 + t * 10 + n2] = (p[n2] >= m3) ? p[n2] : 0.f;
  }
}

// ---------------- attention kernel B — MFMA, head-major bf16, LDS union -----
__global__ __launch_bounds__(256) void attnB_k(
    const unsigned short* __restrict__ fbg, const unsigned short* __restrict__ feg,
    const float* __restrict__ Pg, float* __restrict__ out) {
  __shared__ __align__(16) unsigned U[7616 + 1088];
  unsigned* P2 = U;            // [112][68] (phases C,D)
  unsigned* Qs = U;            // [112][20] (phases A,B; dead before P2 write)
  unsigned* Ks = U + 2240;     // [112][20]
  unsigned* Vt = U + 7616;     // [16][68]
  int m = blockIdx.x % 10;
  int head = blockIdx.x / 10;
  int b = head / 576, rem = head % 576, c = rem / 6, grp = rem % 6;
  const unsigned* fbH = (const unsigned*)fbg + (size_t)head * 8000;
  const unsigned* feH = (const unsigned*)feg + (size_t)head * 8000;
  int t = threadIdx.x;

  // ---- phase A: stage Q, mixed K', V' (+ zero pads) ----
  for (int i = t; i < 896; i += 256) {
    int row = i >> 3, cc = i & 7;
    Qs[row * 20 + 8 + cc] = 0;
    Ks[row * 20 + 8 + cc] = 0;
  }
  for (int i = t; i < 96; i += 256) {
    int row = 100 + (i >> 3), cc = i & 7;
    Qs[row * 20 + cc] = 0;
    Ks[row * 20 + cc] = 0;
  }
  for (int i = t; i < 224; i += 256) {
    int d = i / 14, cc = i % 14;
    Vt[d * 68 + 50 + cc] = 0;
  }
  float p[10];
#pragma unroll
  for (int n2 = 0; n2 < 10; ++n2) p[n2] = Pg[head * 100 + m * 10 + n2];
  for (int i = t; i < 800; i += 256) {
    int s = i >> 3, p8 = i & 7;
    Qs[s * 20 + p8] = fbH[(m * 100 + s) * 8 + p8];
  }
  if (t < 200) {
    int sp = t >> 2, q = t & 3;
    float4 ak0 = make_float4(0.f, 0.f, 0.f, 0.f), ak1 = ak0, av0 = ak0, av1 = ak0;
#pragma unroll
    for (int n2 = 0; n2 < 10; ++n2) {
      if (p[n2] != 0.f) {
        float pe = p[n2];
        int rbase = (n2 * 100 + 2 * sp) * 8 + 2 * q;
        uint2 k01 = *(const uint2*)(fbH + rbase);
        uint2 k23 = *(const uint2*)(fbH + rbase + 8);
        uint2 e01 = *(const uint2*)(feH + rbase);
        uint2 e23 = *(const uint2*)(feH + rbase + 8);
        ak0.x += pe * blo(k01.x); ak0.y += pe * bhi(k01.x);
        ak0.z += pe * blo(k01.y); ak0.w += pe * bhi(k01.y);
        ak1.x += pe * blo(k23.x); ak1.y += pe * bhi(k23.x);
        ak1.z += pe * blo(k23.y); ak1.w += pe * bhi(k23.y);
        av0.x += pe * blo(e01.x); av0.y += pe * bhi(e01.x);
        av0.z += pe * blo(e01.y); av0.w += pe * bhi(e01.y);
        av1.x += pe * blo(e23.x); av1.y += pe * bhi(e23.x);
        av1.z += pe * blo(e23.y); av1.w += pe * bhi(e23.y);
      }
    }
    Ks[(2 * sp) * 20 + 2 * q]         = bfr(ak0.x) | (bfr(ak0.y) << 16);
    Ks[(2 * sp) * 20 + 2 * q + 1]     = bfr(ak0.z) | (bfr(ak0.w) << 16);
    Ks[(2 * sp + 1) * 20 + 2 * q]     = bfr(ak1.x) | (bfr(ak1.y) << 16);
    Ks[(2 * sp + 1) * 20 + 2 * q + 1] = bfr(ak1.z) | (bfr(ak1.w) << 16);
    Vt[(4 * q + 0) * 68 + sp] = bfr(av0.x) | (bfr(av1.x) << 16);
    Vt[(4 * q + 1) * 68 + sp] = bfr(av0.y) | (bfr(av1.y) << 16);
    Vt[(4 * q + 2) * 68 + sp] = bfr(av0.z) | (bfr(av1.z) << 16);
    Vt[(4 * q + 3) * 68 + sp] = bfr(av0.w) | (bfr(av1.w) << 16);
  }
  __syncthreads();

  // ---- phase B: QK^T into registers ----
  int lane = t & 63, w = t >> 6;
  int l15 = lane & 15, kg = lane >> 4;
  int nmt = (w < 3) ? 2 : 1;
  f32x4 s2[2][7];
#pragma unroll
  for (int im = 0; im < 2; ++im) {
    if (im < nmt) {
      int mt = w * 2 + im;
      FragU qf;
      int qbase = (mt * 16 + l15) * 20 + kg * 4;
      qf.u[0] = Qs[qbase + 0]; qf.u[1] = Qs[qbase + 1];
      qf.u[2] = Qs[qbase + 2]; qf.u[3] = Qs[qbase + 3];
#pragma unroll
      for (int nt2 = 0; nt2 < 7; ++nt2) {
        FragU kf;
        int kbase = (nt2 * 16 + l15) * 20 + kg * 4;
        kf.u[0] = Ks[kbase + 0]; kf.u[1] = Ks[kbase + 1];
        kf.u[2] = Ks[kbase + 2]; kf.u[3] = Ks[kbase + 3];
        s2[im][nt2] = __builtin_amdgcn_mfma_f32_16x16x32_bf16(
            qf.v, kf.v, (f32x4){0.f, 0.f, 0.f, 0.f}, 0, 0, 0);
      }
    }
  }
  __syncthreads();

  // ---- phase C: softmax + P2 write ----
  for (int i = t; i < 896; i += 256) {
    int row = i >> 3, cc = i & 7;
    P2[row * 68 + 56 + cc] = 0;
  }
  float rinv[2][4];
#pragma unroll
  for (int im = 0; im < 2; ++im) {
    if (im < nmt) {
      int mt = w * 2 + im;
      if (l15 >= 4) {
        s2[im][6][0] = -3.0e38f; s2[im][6][1] = -3.0e38f;
        s2[im][6][2] = -3.0e38f; s2[im][6][3] = -3.0e38f;
      }
#pragma unroll
      for (int r = 0; r < 4; ++r) {
        float mx = s2[im][0][r];
#pragma unroll
        for (int nt2 = 1; nt2 < 7; ++nt2) mx = fmaxf(mx, s2[im][nt2][r]);
        mx = fmaxf(mx, __shfl_xor(mx, 1, 64));
        mx = fmaxf(mx, __shfl_xor(mx, 2, 64));
        mx = fmaxf(mx, __shfl_xor(mx, 4, 64));
        mx = fmaxf(mx, __shfl_xor(mx, 8, 64));
        float pv[7];
        float sum = 0.f;
#pragma unroll
        for (int nt2 = 0; nt2 < 7; ++nt2) {
          pv[nt2] = __expf((s2[im][nt2][r] - mx) * ITEMP);
          sum += pv[nt2];
        }
        sum += __shfl_xor(sum, 1, 64);
        sum += __shfl_xor(sum, 2, 64);
        sum += __shfl_xor(sum, 4, 64);
        sum += __shfl_xor(sum, 8, 64);
        rinv[im][r] = 1.f / sum;
        int row = mt * 16 + kg * 4 + r;
#pragma unroll
        for (int nt2 = 0; nt2 < 7; ++nt2) {
          float other = __shfl_xor(pv[nt2], 1, 64);
          if ((l15 & 1) == 0)
            P2[row * 68 + nt2 * 8 + (l15 >> 1)] = bfr(pv[nt2]) | (bfr(other) << 16);
        }
      }
    }
  }
  __syncthreads();

  // ---- phase D: PV ----
#pragma unroll
  for (int im = 0; im < 2; ++im) {
    if (im < nmt) {
      int mt = w * 2 + im;
      f32x4 acc = (f32x4){0.f, 0.f, 0.f, 0.f};
#pragma unroll
      for (int ks = 0; ks < 4; ++ks) {
        FragU pa, vb;
        int pbase = (mt * 16 + l15) * 68 + ks * 16 + kg * 4;
        pa.u[0] = P2[pbase + 0]; pa.u[1] = P2[pbase + 1];
        pa.u[2] = P2[pbase + 2]; pa.u[3] = P2[pbase + 3];
        int vbase = l15 * 68 + ks * 16 + kg * 4;
        vb.u[0] = Vt[vbase + 0]; vb.u[1] = Vt[vbase + 1];
        vb.u[2] = Vt[vbase + 2]; vb.u[3] = Vt[vbase + 3];
        acc = __builtin_amdgcn_mfma_f32_16x16x32_bf16(pa.v, vb.v, acc, 0, 0, 0);
      }
      float* obp = out + b * CNW + c * 96000 + grp * 16 + (m * 100) * 96 + l15;
#pragma unroll
      for (int r = 0; r < 4; ++r) {
        int row = mt * 16 + kg * 4 + r;
        if (row < 100) obp[row * 96] = acc[r] * rinv[im][r];
      }
    }
  }
}

// ------ trans_add: A2 = bf16-pairs of swapaxes(feat_attn,1,3)+x, GN stats ---
__global__ __launch_bounds__(256) void trans_add_k(const float* __restrict__ z,
    const float* __restrict__ x, unsigned* __restrict__ a2,
    float* __restrict__ rawGN) {
  __shared__ float ld[96 * 97];
  __shared__ float red[4 * 12];
  int b = blockIdx.x / 1000, n = blockIdx.x % 1000;
  int t = threadIdx.x;
  const float* zp = z + b * CNW + n * 96;
  for (int i = t; i < 9216; i += 256) {
    int r = i / 96, col = i % 96;
    ld[r * 97 + col] = zp[r * 96000 + col];
  }
  __syncthreads();
  const float* xp = x + b * CNW + n * 96;
  unsigned* ab = a2 + (size_t)b * 1500 * 3072;
  float sg[6], qg[6];
#pragma unroll
  for (int g = 0; g < 6; ++g) { sg[g] = 0.f; qg[g] = 0.f; }
#pragma unroll
  for (int k = 0; k < 18; ++k) {
    int i = t + k * 256;
    int g = k / 3;                    // = i/768, compile-time under unroll
    int cc2 = i / 96, ww = i % 96;
    int c0 = 2 * cc2;
    float v0 = ld[ww * 97 + c0] + xp[c0 * 96000 + ww];
    float v1 = ld[ww * 97 + c0 + 1] + xp[(c0 + 1) * 96000 + ww];
    int nw = n * 96 + ww;
    ab[(size_t)(nw >> 6) * 3072 + cc2 * 64 + (nw & 63)] = bfr(v0) | (bfr(v1) << 16);
    sg[g] += v0 + v1;
    qg[g] += v0 * v0 + v1 * v1;
  }
#pragma unroll
  for (int msk = 1; msk <= 32; msk <<= 1)
#pragma unroll
    for (int g = 0; g < 6; ++g) {
      sg[g] += __shfl_xor(sg[g], msk, 64);
      qg[g] += __shfl_xor(qg[g], msk, 64);
    }
  int wid = t >> 6;
  if ((t & 63) == 0)
#pragma unroll
    for (int g = 0; g < 6; ++g) {
      red[wid * 12 + g * 2 + 0] = sg[g];
      red[wid * 12 + g * 2 + 1] = qg[g];
    }
  __syncthreads();
  if (t < 12) {
    float s = red[t] + red[12 + t] + red[24 + t] + red[36 + t];
    atomicAdd(&rawGN[(n & (NREP - 1)) * 24 + b * 12 + t], s);
  }
}

// ---------------- out = relu( BN2(IN(l2)) + BNr(right) ), bf16 inputs -------
__global__ __launch_bounds__(256) void final_k(float* __restrict__ outp,
    const unsigned short* __restrict__ rightb, const unsigned short* __restrict__ l2b,
    const float* __restrict__ stR, const float* __restrict__ st2,
    const float* __restrict__ rw, const float* __restrict__ rb,
    const float* __restrict__ w2, const float* __restrict__ b2) {
  int stride = gridDim.x * 256;
  for (int i4 = blockIdx.x * 256 + threadIdx.x; i4 < 4608000; i4 += stride) {
    int i = i4 * 4;
    int b = i / CNW, o = (i / 96000) % 96;
    float mr = (stR[o * 2] + stR[192 + o * 2]) * (1.f / 192000.f);
    float vr = (stR[o * 2 + 1] + stR[192 + o * 2 + 1]) * (1.f / 192000.f) - mr * mr;
    float rs = rsqrtf(vr + EPSV) * rw[o];
    float rsh = rb[o] - mr * rs;
    const float inv = 1.f / 96000.f;
    float m0 = st2[o * 2] * inv,       v0 = st2[o * 2 + 1] * inv - m0 * m0;
    float m1 = st2[192 + o * 2] * inv, v1 = st2[192 + o * 2 + 1] * inv - m1 * m1;
    float bv = 0.5f * (v0 / (v0 + EPSV) + v1 / (v1 + EPSV));
    float ls = rsqrtf(bv + EPSV) * w2[o];
    float mi = b ? m1 : m0, vi = b ? v1 : v0;
    float lsc = rsqrtf(vi + EPSV) * ls;
    float lsh = b2[o] - mi * lsc;
    uint2 Ru = ((const uint2*)rightb)[i4];
    uint2 Lu = ((const uint2*)l2b)[i4];
    float4 O;
    O.x = fmaxf(blo(Ru.x) * rs + rsh + blo(Lu.x) * lsc + lsh, 0.f);
    O.y = fmaxf(bhi(Ru.x) * rs + rsh + bhi(Lu.x) * lsc + lsh, 0.f);
    O.z = fmaxf(blo(Ru.y) * rs + rsh + blo(Lu.y) * lsc + lsh, 0.f);
    O.w = fmaxf(bhi(Ru.y) * rs + rsh + bhi(Lu.y) * lsc + lsh, 0.f);
    ((float4*)outp)[i4] = O;
  }
}

extern "C" void kernel_launch(void* const* d_in, const int* in_sizes, int n_in,
                              void* d_out, int out_size, void* d_ws, size_t ws_size,
                              hipStream_t stream) {
  const float* x        = (const float*)d_in[0];
  const float* w_linear = (const float*)d_in[1];
  const float* gn_w     = (const float*)d_in[2];
  const float* gn_b     = (const float*)d_in[3];
  const float* w_right  = (const float*)d_in[4];
  const float* b_right  = (const float*)d_in[5];
  const float* bn_r_w   = (const float*)d_in[6];
  const float* bn_r_b   = (const float*)d_in[7];
  const float* w_l1     = (const float*)d_in[8];
  const float* b_l1     = (const float*)d_in[9];
  const float* bn1_w    = (const float*)d_in[10];
  const float* bn1_b    = (const float*)d_in[11];
  const float* w_l2     = (const float*)d_in[12];
  const float* b_l2     = (const float*)d_in[13];
  const float* bn2_w    = (const float*)d_in[14];
  const float* bn2_b    = (const float*)d_in[15];
  float* out = (float*)d_out;

  // region0 (TOT floats): featb+felub -> a2 aliases featb, rightb aliases
  // felub, l2b aliases featb (after a2 consumed)
  float* A      = (float*)d_ws;
  unsigned short* featb = (unsigned short*)A;     // TOT ushorts (head-major)
  unsigned short* felub = featb + TOT;            // TOT ushorts (head-major)
  unsigned* a2  = (unsigned*)featb;               // TOT/2 u32
  unsigned short* rightb = felub;                 // TOT ushorts (bf16 right)
  unsigned short* l2b    = featb;                 // TOT ushorts (bf16 l2)
  // region1 (TOT floats): Bb fp32 attn-out -> a2L aliases after trans_add
  float* Bb     = A + TOT;
  unsigned* a2L = (unsigned*)Bb;                  // TOT/2 u32 (packed l1)
  float* Pg     = Bb + TOT;                // 115200
  float* rawGN  = Pg + 115200;             // NREP*24 = 384
  float* rawBNr = rawGN + NREP * 24;       // NREP*384
  float* rawIN1 = rawBNr + NREP * 384;     // NREP*384
  float* rawIN2 = rawIN1 + NREP * 384;     // NREP*384
  float* stBNr  = rawIN2 + NREP * 384;     // 384
  float* stIN2  = stBNr + 384;             // 384
  unsigned* w2_0  = (unsigned*)(stIN2 + 384);  // 4704
  unsigned* w2R   = w2_0 + 4704;               // 2*4704
  unsigned* w2L   = w2R + 2 * 4704;            // 2*4704
  unsigned* w2l2  = w2L + 2 * 4704;            // 4704
  float* b2R   = (float*)(w2l2 + 4704);        // 192
  float* b2L   = b2R + 192;                    // 192
  float* b2l2  = b2L + 192;                    // 192
  float* scl1g = b2l2 + 192;                   // 192
  float* shf1g = scl1g + 192;                  // 192
  float* xm    = shf1g + 192;                  // 184320
  float* qmg   = xm + 184320;                  // 184320

  hipMemsetAsync(rawGN, 0, (NREP * 24 + 3 * NREP * 384) * sizeof(float), stream);

  prep0_k<<<1, 256, 0, stream>>>(w_linear, w2_0);
  // feat (+elu) = conv1x1(x, w_linear) -> featb/felub (head-major bf16, MFMA)
  convb0_k<<<3000, 256, 0, stream>>>(x, w2_0, featb, felub);
  // exact fp32 path for the sinkhorn cut: xm = mean_s(x), qm = W @ xm
  xmean_k<<<1920, 128, 0, stream>>>(x, xm);
  qm_k<<<20, 256, 0, stream>>>(xm, w_linear, qmg);
  attnA_k<<<1152, 256, 0, stream>>>(qmg, Pg);
  // attention -> Bb
  attnB_k<<<11520, 256, 0, stream>>>(featb, felub, Pg, Bb);
  // A2 = bf16-pair(t + x) in conv layout (featb dead); fused GN stats
  trans_add_k<<<2000, 256, 0, stream>>>(Bb, x, a2, rawGN);
  prep_rl_k<<<1, 256, 0, stream>>>(rawGN, w_right, b_right, w_l1, b_l1,
                                   gn_w, gn_b, w2R, b2R, w2L, b2L);
  // fused right + l1 convs from A2: right -> bf16 (felub region),
  // l1 -> packed a2L (Bb region, dead after trans_add)
  convm2_k<<<3000, 256, 0, stream>>>(a2, w2R, b2R, w2L, b2L,
                                     rightb, a2L, rawBNr, rawIN1);
  prep_l2_k<<<1, 256, 0, stream>>>(rawIN1, w_l2, b_l2, bn1_w, bn1_b,
                                   w2l2, b2l2, scl1g, shf1g);
  // l2 = conv(relu(BN1(IN(l1)))) from packed a2L -> l2b bf16 (a2 dead)
  convmP_k<<<3000, 256, 0, stream>>>(a2L, w2l2, b2l2, scl1g, shf1g,
                                     l2b, rawIN2);
  collapse_k<<<3, 256, 0, stream>>>(rawBNr, stBNr, rawIN2, stIN2);
  // out = relu(BN2(IN(l2)) + BNr(right)), bf16 inputs -> fp32 d_out
  final_k<<<2048, 256, 0, stream>>>(out, rightb, l2b, stBNr, stIN2,
                                    bn_r_w, bn_r_b, bn2_w, bn2_b);
}